// Round 10
// baseline (643.524 us; speedup 1.0000x reference)
//
#include <hip/hip_runtime.h>
#include <math.h>

#define NB 2
#define NY 360
#define NX 720
#define NZ 32
#define NPTS (NB*NY*NX*NZ)     // 16,588,800
#define NCOL (NB*NY*NX)        // 518,400

__device__ __forceinline__ int i4(int b,int y,int x,int z){ return (((b*NY)+y)*NX+x)*NZ+z; }
__device__ __forceinline__ int i3(int b,int y,int x){ return ((b*NY)+y)*NX+x; }

#define F_RAD   6371000.0f
#define F_OMEGA 7.292e-5f
#define F_CP    1004.0f
#define F_DLAT  ((float)(M_PI/360.0))                 /* == dlon */
#define F_DYR   ((float)(M_PI/360.0*6371000.0))      /* dlat*RAD */
#define F_HPI   ((float)(M_PI/2.0))
#define TH      ((float)(2.0*M_PI/720.0))

// -------------------- kernel 1: div_h = du/dx + dv/dy --------------------
__global__ __launch_bounds__(256) void k_divh(const float* __restrict__ u,
                                              const float* __restrict__ v,
                                              float* __restrict__ divh) {
  int gid = blockIdx.x*256 + threadIdx.x;          // exact: 64800*256 = NPTS
  int z  = gid & 31;
  int x  = (gid >> 5) % NX;
  int by = gid / (NX*NZ);
  int y  = by % NY;
  int b  = by / NY;
  float lat = -F_HPI + (y+0.5f)*F_DLAT;
  float cl  = cosf(lat);
  float invdx = 0.5f/(F_DLAT*F_RAD*cl);
  int xp = (x==NX-1)?0:x+1, xm = (x==0)?NX-1:x-1;
  float dudx = (u[i4(b,y,xp,z)] - u[i4(b,y,xm,z)]) * invdx;
  float dvdy;
  if (y == 0)          dvdy = (v[i4(b,1,x,z)]    - v[i4(b,0,x,z)])    * (1.0f/F_DYR);
  else if (y == NY-1)  dvdy = (v[i4(b,NY-1,x,z)] - v[i4(b,NY-2,x,z)]) * (1.0f/F_DYR);
  else                 dvdy = (v[i4(b,y+1,x,z)]  - v[i4(b,y-1,x,z)])  * (0.5f/F_DYR);
  divh[gid] = dudx + dvdy;
}

// -------------------- kernel 2: all raw tendencies --------------------
__global__ __launch_bounds__(256) void k_tend(
    const float* __restrict__ u, const float* __restrict__ v,
    const float* __restrict__ T, const float* __restrict__ ps,
    const float* __restrict__ Rp, const float* __restrict__ divh,
    float* __restrict__ du, float* __restrict__ dv,
    float* __restrict__ dT, float* __restrict__ dps) {
  const int tid = threadIdx.x;
  const int z   = tid & 31;
  const int col = blockIdx.x*8 + (tid>>5);         // exact: 64800*8 = NCOL
  const int x = col % NX;
  const int y = (col / NX) % NY;
  const int b = col / (NX*NY);
  const float R = Rp[0];

  const int xp = (x==NX-1)?0:x+1, xm = (x==0)?NX-1:x-1;
  const int ycm = (y>0)? y-1 : 0;
  const int ycp = (y<NY-1)? y+1 : NY-1;
  const bool y0 = (y==0), yN = (y==NY-1);

  const float lat  = -F_HPI + (y+0.5f)*F_DLAT;
  const float cl   = cosf(lat);
  const float fcor = 2.0f*F_OMEGA*sinf(lat);
  const float sx     = F_DLAT*F_RAD*cl;
  const float invdx  = 0.5f/sx;
  const float inv2dy = 0.5f/F_DYR;
  const float inv1dy = 1.0f/F_DYR;
  const float invsx2 = 1.0f/(sx*sx);
  const float invsy2 = 1.0f/(F_DYR*F_DYR);
  const float bk  = (z + 0.5f)/32.0f;
  const float dsv = 1.0f/32.0f;

  const int ic  = i4(b,y,x,z),   ixp = i4(b,y,xp,z), ixm = i4(b,y,xm,z);
  const int iyp = i4(b,ycp,x,z), iym = i4(b,ycm,x,z);

  const float uc=u[ic], uxp=u[ixp], uxm=u[ixm], uyp=u[iyp], uym=u[iym];
  const float vc=v[ic], vxp=v[ixp], vxm=v[ixm], vyp=v[iyp], vym=v[iym];
  const float Tc=T[ic], Txp=T[ixp], Txm=T[ixm], Typ=T[iyp], Tym=T[iym];
  const float Dc=divh[ic], Dxp=divh[ixp], Dxm=divh[ixm], Dyp=divh[iyp], Dym=divh[iym];
  const float psc=ps[i3(b,y,x)],   psxp=ps[i3(b,y,xp)], psxm=ps[i3(b,y,xm)];
  const float psyp=ps[i3(b,ycp,x)], psym=ps[i3(b,ycm,x)];

  auto dfy = [&](float fc_, float fyp_, float fym_) -> float {
    if (y0) return (fyp_ - fc_) * inv1dy;
    if (yN) return (fc_ - fym_) * inv1dy;
    return (fyp_ - fym_) * inv2dy;
  };
  auto lap = [&](float fc_, float fxp_, float fxm_, float fyp_, float fym_) -> float {
    float d2x = (fxp_ + fxm_ - 2.0f*fc_) * invsx2;
    float d2y = (y0||yN) ? 0.0f : (fyp_ + fym_ - 2.0f*fc_) * invsy2;
    return d2x + d2y;
  };
  auto sufscan = [&](float vv) -> float {   // vv[z] = sum_{j>=z}
    #pragma unroll
    for (int d=1; d<32; d<<=1) { float t = __shfl_down(vv, d, 32); if (z+d<32) vv += t; }
    return vv;
  };
  auto prescan = [&](float vv) -> float {   // vv[z] = sum_{j<=z}
    #pragma unroll
    for (int d=1; d<32; d<<=1) { float t = __shfl_up(vv, d, 32); if (z>=d) vv += t; }
    return vv;
  };
  auto vg = [&](float fc_) -> float {       // d/dsigma
    float fzp = __shfl_down(fc_,1,32), fzm = __shfl_up(fc_,1,32);
    if (z==0)  return (fzp - fc_) * 32.0f;
    if (z==31) return (fc_ - fzm) * 32.0f;
    return (fzp - fzm) * 16.0f;
  };

  const float rz = dsv / bk;
  const float phic  = sufscan(R*Tc*rz);
  const float phixp = sufscan(R*Txp*rz);
  const float phixm = sufscan(R*Txm*rz);
  const float phiyp = sufscan(R*Typ*rz);
  const float phiym = sufscan(R*Tym*rz);

  const float dudx = (uxp-uxm)*invdx, dvdx = (vxp-vxm)*invdx, dTdx = (Txp-Txm)*invdx;
  const float dphidx = (phixp-phixm)*invdx;
  const float dudy = dfy(uc,uyp,uym), dvdy_ = dfy(vc,vyp,vym), dTdy = dfy(Tc,Typ,Tym);
  const float dphidy = dfy(phic,phiyp,phiym);
  const float dpsdx = (psxp-psxm)*invdx, dpsdy = dfy(psc,psyp,psym);
  const float gdivx = (Dxp-Dxm)*invdx,  gdivy = dfy(Dc,Dyp,Dym);

  const float mass = Dc*psc + uc*dpsdx + vc*dpsdy;
  float Ipre = prescan(mass) * dsv;
  const float Itot = __shfl(Ipre, 31, 32);
  const float sigd = (bk*Itot - Ipre) / (psc + 1e-8f);

  const float vgu = vg(uc), vgv = vg(vc), vgT = vg(Tc);

  const float pfac = R*Tc*bk/(bk*psc + 1e-8f);
  const float pgfu = -dphidx - pfac*dpsdx;
  const float pgfv = -dphidy - pfac*dpsdy;
  const float cf2  = fmaxf(cl*cl, 0.01f);
  const float nudiv = 500000.0f*cf2, nuh = 100000.0f*cf2;
  const float lapu = lap(uc,uxp,uxm,uyp,uym);
  const float lapv = lap(vc,vxp,vxm,vyp,vym);
  const float lapT = lap(Tc,Txp,Txm,Typ,Tym);
  const float adiab = R*Tc/(bk*psc*F_CP + 1e-8f) * (sigd*psc);

  float dut = -(uc*dudx + vc*dudy)  - sigd*vgu + fcor*vc + pgfu + nuh*lapu - 1e-5f*uc + nudiv*gdivx;
  float dvt = -(uc*dvdx + vc*dvdy_) - sigd*vgv - fcor*uc + pgfv + nuh*lapv - 1e-5f*vc + nudiv*gdivy;
  float dTt = -(uc*dTdx + vc*dTdy)  - sigd*vgT + adiab + nuh*lapT;

  du[ic] = dut; dv[ic] = dvt; dT[ic] = dTt;
  if (z == 0) dps[i3(b,y,x)] = -Itot;
}

// -------------------- polar filter helpers --------------------
__device__ __forceinline__ void filter_band(int y, int& k0, int& k1, bool& keepmode) {
  float lat = -F_HPI + (y+0.5f)*F_DLAT;
  float cut = fmaxf(360.0f*cosf(lat), 1.0f);
  int M = (int)floorf(cut);
  keepmode = (M <= 179);
  k0 = keepmode ? 0 : (M+1);
  k1 = keepmode ? M : 360;
}

// analysis inner-loop steps: TWO same-residue k's (k, k+4) share every LDS
// read — the filter is LDS-instruction-throughput bound (~12cyc/ds_read_b128),
// so FMA:read ratio is the lever. Per-accumulator arithmetic order unchanged.
#define EVEN_STEP2 { \
  const float4 a  = *(const float4*)(Sp + i*8); \
  const float4 b4 = *(const float4*)(Sp + i*8 + 4); \
  acA[0]=fmaf(a.x ,cA,acA[0]); asA[0]=fmaf(a.x ,sA,asA[0]); \
  acA[1]=fmaf(a.y ,cA,acA[1]); asA[1]=fmaf(a.y ,sA,asA[1]); \
  acA[2]=fmaf(a.z ,cA,acA[2]); asA[2]=fmaf(a.z ,sA,asA[2]); \
  acA[3]=fmaf(a.w ,cA,acA[3]); asA[3]=fmaf(a.w ,sA,asA[3]); \
  acA[4]=fmaf(b4.x,cA,acA[4]); asA[4]=fmaf(b4.x,sA,asA[4]); \
  acA[5]=fmaf(b4.y,cA,acA[5]); asA[5]=fmaf(b4.y,sA,asA[5]); \
  acA[6]=fmaf(b4.z,cA,acA[6]); asA[6]=fmaf(b4.z,sA,asA[6]); \
  acA[7]=fmaf(b4.w,cA,acA[7]); asA[7]=fmaf(b4.w,sA,asA[7]); \
  acB[0]=fmaf(a.x ,cB,acB[0]); asB[0]=fmaf(a.x ,sB,asB[0]); \
  acB[1]=fmaf(a.y ,cB,acB[1]); asB[1]=fmaf(a.y ,sB,asB[1]); \
  acB[2]=fmaf(a.z ,cB,acB[2]); asB[2]=fmaf(a.z ,sB,asB[2]); \
  acB[3]=fmaf(a.w ,cB,acB[3]); asB[3]=fmaf(a.w ,sB,asB[3]); \
  acB[4]=fmaf(b4.x,cB,acB[4]); asB[4]=fmaf(b4.x,sB,asB[4]); \
  acB[5]=fmaf(b4.y,cB,acB[5]); asB[5]=fmaf(b4.y,sB,asB[5]); \
  acB[6]=fmaf(b4.z,cB,acB[6]); asB[6]=fmaf(b4.z,sB,asB[6]); \
  acB[7]=fmaf(b4.w,cB,acB[7]); asB[7]=fmaf(b4.w,sB,asB[7]); \
  { const float nA = fmaf(cA, dcA, -sA*dsA); sA = fmaf(sA, dcA, cA*dsA); cA = nA; } \
  { const float nB = fmaf(cB, dcB, -sB*dsB); sB = fmaf(sB, dcB, cB*dsB); cB = nB; } }

#define ODD_STEP2 { \
  const float4 p0 = *(const float4*)(Ap + i*16); \
  const float4 p1 = *(const float4*)(Ap + i*16 + 4); \
  const float4 p2 = *(const float4*)(Ap + i*16 + 8); \
  const float4 p3 = *(const float4*)(Ap + i*16 + 12); \
  { const float sgc = sg*cA, sgs = sg*sA; \
    acA[0]=fmaf(p0.x,cA,fmaf(p0.y,-sgs,acA[0])); asA[0]=fmaf(p0.x,sA,fmaf(p0.y,sgc,asA[0])); \
    acA[1]=fmaf(p0.z,cA,fmaf(p0.w,-sgs,acA[1])); asA[1]=fmaf(p0.z,sA,fmaf(p0.w,sgc,asA[1])); \
    acA[2]=fmaf(p1.x,cA,fmaf(p1.y,-sgs,acA[2])); asA[2]=fmaf(p1.x,sA,fmaf(p1.y,sgc,asA[2])); \
    acA[3]=fmaf(p1.z,cA,fmaf(p1.w,-sgs,acA[3])); asA[3]=fmaf(p1.z,sA,fmaf(p1.w,sgc,asA[3])); \
    acA[4]=fmaf(p2.x,cA,fmaf(p2.y,-sgs,acA[4])); asA[4]=fmaf(p2.x,sA,fmaf(p2.y,sgc,asA[4])); \
    acA[5]=fmaf(p2.z,cA,fmaf(p2.w,-sgs,acA[5])); asA[5]=fmaf(p2.z,sA,fmaf(p2.w,sgc,asA[5])); \
    acA[6]=fmaf(p3.x,cA,fmaf(p3.y,-sgs,acA[6])); asA[6]=fmaf(p3.x,sA,fmaf(p3.y,sgc,asA[6])); \
    acA[7]=fmaf(p3.z,cA,fmaf(p3.w,-sgs,acA[7])); asA[7]=fmaf(p3.z,sA,fmaf(p3.w,sgc,asA[7])); } \
  { const float sgc = sg*cB, sgs = sg*sB; \
    acB[0]=fmaf(p0.x,cB,fmaf(p0.y,-sgs,acB[0])); asB[0]=fmaf(p0.x,sB,fmaf(p0.y,sgc,asB[0])); \
    acB[1]=fmaf(p0.z,cB,fmaf(p0.w,-sgs,acB[1])); asB[1]=fmaf(p0.z,sB,fmaf(p0.w,sgc,asB[1])); \
    acB[2]=fmaf(p1.x,cB,fmaf(p1.y,-sgs,acB[2])); asB[2]=fmaf(p1.x,sB,fmaf(p1.y,sgc,asB[2])); \
    acB[3]=fmaf(p1.z,cB,fmaf(p1.w,-sgs,acB[3])); asB[3]=fmaf(p1.z,sB,fmaf(p1.w,sgc,asB[3])); \
    acB[4]=fmaf(p2.x,cB,fmaf(p2.y,-sgs,acB[4])); asB[4]=fmaf(p2.x,sB,fmaf(p2.y,sgc,asB[4])); \
    acB[5]=fmaf(p2.z,cB,fmaf(p2.w,-sgs,acB[5])); asB[5]=fmaf(p2.z,sB,fmaf(p2.w,sgc,asB[5])); \
    acB[6]=fmaf(p3.x,cB,fmaf(p3.y,-sgs,acB[6])); asB[6]=fmaf(p3.x,sB,fmaf(p3.y,sgc,asB[6])); \
    acB[7]=fmaf(p3.z,cB,fmaf(p3.w,-sgs,acB[7])); asB[7]=fmaf(p3.z,sB,fmaf(p3.w,sgc,asB[7])); } \
  { const float nA = fmaf(cA, dcA, -sA*dsA); sA = fmaf(sA, dcA, cA*dsA); cA = nA; } \
  { const float nB = fmaf(cB, dcB, -sB*dsB); sB = fmaf(sB, dcB, cB*dsB); cB = nB; } }

// -------------------- kernel 3: folded-DFT polar filter, all outputs ------
// Grid 9360 = 8640 field blocks + 720 dpsdt blocks. Analysis: 4 residue
// classes (order 0,2,1,3 -> waves 0-2 even-path, 3-5 odd-path, no wave
// divergence), 24 slots/class, 2 same-residue k's per slot sharing LDS reads.
#define FKMAX 180
__global__ __launch_bounds__(384, 4) void k_filter4b(
    float* __restrict__ du, float* __restrict__ dv, float* __restrict__ dT,
    float* __restrict__ dps, float* __restrict__ dq) {
  __shared__ __align__(16) float smem[8640];   // 34.56 KB

  const int tid = threadIdx.x;
  // bijective XCD-chunk swizzle: 9360 = 8 * 1170
  const int bid = (blockIdx.x & 7) * 1170 + (blockIdx.x >> 3);

  if (bid >= 8640) {
    // ---------------- dpsdt filter path (720 blocks) ----------------
    float*  f  = smem;                          // [720]
    float2* tw = (float2*)(smem + 720);         // [720]
    float*  sc = smem + 720 + 1440;             // [184]
    float*  ss = sc + 184;
    const int row = bid - 8640;                 // 0..719 = b*360+y
    const int y = row % NY;
    float* base = dps + (size_t)row*NX;
    for (int t = tid; t < NX; t += 384) {
      float a = (float)t * TH;
      float sv, cv; sincosf(a, &sv, &cv);
      tw[t] = make_float2(cv, sv);
      f[t] = base[t];
    }
    int k0, k1; bool keepmode;
    filter_band(y, k0, k1, keepmode);
    const int nk = k1 - k0 + 1;
    __syncthreads();
    if (tid < nk) {
      const int k = k0 + tid;
      float ac=0.f, as=0.f; int idx=0;
      for (int xx=0; xx<NX; ++xx) {
        const float fv = f[xx];
        const float2 t2 = tw[idx];
        ac = fmaf(fv, t2.x, ac); as = fmaf(fv, t2.y, as);
        idx += k; if (idx >= NX) idx -= NX;
      }
      sc[tid]=ac; ss[tid]=as;
    }
    __syncthreads();
    if (tid < 360) {
      const int x0 = tid, x1 = tid + 360;
      const int t0 = (x0 * k0) % NX;
      const int t1 = (x1 * k0) % NX;
      float c0 = tw[t0].x, s0 = tw[t0].y;
      float c1 = tw[t1].x, s1 = tw[t1].y;
      const float dc0 = tw[x0].x, dn0 = tw[x0].y;
      const float dc1 = tw[x1].x, dn1 = tw[x1].y;
      float a0 = 0.f, a1 = 0.f;
      for (int kk = 0; kk < nk; ++kk) {
        const int k = k0 + kk;
        const float w = (k==0 || k==360) ? 1.0f : 2.0f;
        a0 = fmaf(sc[kk], w*c0, fmaf(ss[kk], w*s0, a0));
        a1 = fmaf(sc[kk], w*c1, fmaf(ss[kk], w*s1, a1));
        float n0 = c0*dc0 - s0*dn0; s0 = c0*dn0 + s0*dc0; c0 = n0;
        float n1 = c1*dc1 - s1*dn1; s1 = c1*dn1 + s1*dc1; c1 = n1;
      }
      const float inv = 1.0f/720.0f;
      float o0 = keepmode ? a0*inv : f[x0] - a0*inv;
      float o1 = keepmode ? a1*inv : f[x1] - a1*inv;
      o0 = fminf(fmaxf(o0, -0.5f), 0.5f);
      o1 = fminf(fmaxf(o1, -0.5f), 0.5f);
      base[x0] = o0;
      base[x1] = o1;
    }
    return;
  }

  // ---------------- field filter path (8640 blocks) ----------------
  float (*S0)[8]    = (float(*)[8])   smem;           // [180][8]
  float (*S2)[8]    = (float(*)[8])  (smem + 1440);   // [180][8]
  float (*AB)[8][2] = (float(*)[8][2])(smem + 2880);  // [180][8][2]
  float (*SD)[8][2] = (float(*)[8][2])(smem + 5760);  // [180][8][2]

  // fused k_zero: each field block zeroes its 1920-float dq slice
  {
    float4* dqv = (float4*)dq + (size_t)bid * 480;
    const float4 z4 = make_float4(0.f,0.f,0.f,0.f);
    for (int t = tid; t < 480; t += 384) dqv[t] = z4;
  }

  const int zq   = bid & 3;
  const int rest = bid >> 2;
  const int by   = rest % (NB*NY);
  const int fld  = rest / (NB*NY);
  const int y = by % NY, b = by / NY;
  float* fptr = (fld==0)? du : (fld==1)? dv : dT;
  const float clipv = (fld==2)? 0.01f : 0.02f;
  float* base = fptr + ((size_t)(b*NY+y)*NX)*NZ + zq*8;

  int k0, k1; bool keep;
  filter_band(y, k0, k1, keep);

  // ---- load + fold ----
  if (tid < 360) {
    const int x  = tid % 180;
    const int zh = tid / 180;                       // 0/1 -> z offset 4*zh
    const float4 q0 = *(const float4*)(base + (size_t)(x      )*NZ + zh*4);
    const float4 q1 = *(const float4*)(base + (size_t)(x + 180)*NZ + zh*4);
    const float4 q2 = *(const float4*)(base + (size_t)(x + 360)*NZ + zh*4);
    const float4 q3 = *(const float4*)(base + (size_t)(x + 540)*NZ + zh*4);
    float4 s0v, s2v, av, bv;
    s0v.x=q0.x+q1.x+q2.x+q3.x; s2v.x=q0.x-q1.x+q2.x-q3.x; av.x=q0.x-q2.x; bv.x=q1.x-q3.x;
    s0v.y=q0.y+q1.y+q2.y+q3.y; s2v.y=q0.y-q1.y+q2.y-q3.y; av.y=q0.y-q2.y; bv.y=q1.y-q3.y;
    s0v.z=q0.z+q1.z+q2.z+q3.z; s2v.z=q0.z-q1.z+q2.z-q3.z; av.z=q0.z-q2.z; bv.z=q1.z-q3.z;
    s0v.w=q0.w+q1.w+q2.w+q3.w; s2v.w=q0.w-q1.w+q2.w-q3.w; av.w=q0.w-q2.w; bv.w=q1.w-q3.w;
    *(float4*)&S0[x][zh*4] = s0v;
    *(float4*)&S2[x][zh*4] = s2v;
    *(float4*)&AB[x][zh*4+0][0] = make_float4(av.x, bv.x, av.y, bv.y);
    *(float4*)&AB[x][zh*4+2][0] = make_float4(av.z, bv.z, av.w, bv.w);
  }
  __syncthreads();

  // ---- analysis: thread = (ks 0..95, xq 0..3); TWO k's (k, k+4), 8 z ----
  {
    const int xq = tid & 3;
    const int ks = tid >> 2;            // 0..95
    // class order {0,2,1,3}: waves 0-2 even residues, 3-5 odd residues
    const bool isodd = (ks >= 48);
    const int m = ks % 24;
    const int r = isodd ? ((ks < 72) ? 1 : 3) : ((ks < 24) ? 0 : 2);
    const int kst = k0 + ((r - k0) & 3);        // first k >= k0 with k%4 == r
    const int ka = kst + 8*m;
    const int kb = ka + 4;
    const bool aa = (ka <= k1);
    const bool ab = (kb <= k1);
    const int x0 = 45*xq;

    float acA[8], asA[8], acB[8], asB[8];
    #pragma unroll
    for (int j=0;j<8;++j){ acA[j]=0.f; asA[j]=0.f; acB[j]=0.f; asB[j]=0.f; }

    if (aa) {
      float dcA, dsA, dcB, dsB;
      sincosf((float)ka * TH, &dsA, &dcA);
      sincosf((float)kb * TH, &dsB, &dcB);
      float cA, sA, cB, sB;
      sincosf((float)((ka * x0) % 720) * TH, &sA, &cA);
      sincosf((float)((kb * x0) % 720) * TH, &sB, &cB);
      if (!isodd) {
        const float* Sp = ((r == 0) ? &S0[0][0] : &S2[0][0]) + x0*8;
        #pragma unroll 5
        for (int i = 0; i < 45; ++i) EVEN_STEP2
      } else {
        const float sg = (r == 1) ? 1.0f : -1.0f;
        const float* Ap = &AB[x0][0][0];
        #pragma unroll 3
        for (int i = 0; i < 45; ++i) ODD_STEP2
      }
    }
    // combine partial sums over the 4-lane xq group
    #pragma unroll
    for (int j=0;j<8;++j){
      acA[j] += __shfl_xor(acA[j], 1); asA[j] += __shfl_xor(asA[j], 1);
      acB[j] += __shfl_xor(acB[j], 1); asB[j] += __shfl_xor(asB[j], 1);
      acA[j] += __shfl_xor(acA[j], 2); asA[j] += __shfl_xor(asA[j], 2);
      acB[j] += __shfl_xor(acB[j], 2); asB[j] += __shfl_xor(asB[j], 2);
    }
    if (aa && xq == 0) {
      const float w = (ka==0 || ka==360) ? 1.0f : 2.0f;
      const int ra = ka - k0;
      *(float4*)&SD[ra][0][0] = make_float4(w*acA[0], w*asA[0], w*acA[1], w*asA[1]);
      *(float4*)&SD[ra][2][0] = make_float4(w*acA[2], w*asA[2], w*acA[3], w*asA[3]);
      *(float4*)&SD[ra][4][0] = make_float4(w*acA[4], w*asA[4], w*acA[5], w*asA[5]);
      *(float4*)&SD[ra][6][0] = make_float4(w*acA[6], w*asA[6], w*acA[7], w*asA[7]);
    }
    if (ab && xq == 1) {
      const float w = (kb==0 || kb==360) ? 1.0f : 2.0f;
      const int rb = kb - k0;
      *(float4*)&SD[rb][0][0] = make_float4(w*acB[0], w*asB[0], w*acB[1], w*asB[1]);
      *(float4*)&SD[rb][2][0] = make_float4(w*acB[2], w*asB[2], w*acB[3], w*asB[3]);
      *(float4*)&SD[rb][4][0] = make_float4(w*acB[4], w*asB[4], w*acB[5], w*asB[5]);
      *(float4*)&SD[rb][6][0] = make_float4(w*acB[6], w*asB[6], w*acB[7], w*asB[7]);
    }
  }
  __syncthreads();

  // ---- synthesis: thread = (x' 0..179, z-half 0..1), 4 z each ----
  if (tid < 360) {
    const int x  = tid % 180;
    const int zh = tid / 180;
    float HreE[2][4]; float Hro[2][4]; float Hio[2][4];
    #pragma unroll
    for (int i = 0; i < 2; ++i)
      #pragma unroll
      for (int j = 0; j < 4; ++j) { HreE[i][j]=0.f; Hro[i][j]=0.f; Hio[i][j]=0.f; }

    const int m4 = (4*x) % 720;
    float dstep_s, dstep_c; sincosf((float)m4 * TH, &dstep_s, &dstep_c);

    // even residues r=0,2: only Re needed
    #pragma unroll
    for (int ri = 0; ri < 2; ++ri) {
      const int r = ri*2;
      const int kst = k0 + ((r - (k0 & 3) + 4) & 3);
      if (kst > k1) continue;
      int mm = (kst * x) % 720;
      float sv, cv; sincosf((float)mm * TH, &sv, &cv);
      #pragma unroll 2
      for (int k = kst; k <= k1; k += 4) {
        const float4 d01 = *(const float4*)&SD[k - k0][zh*4 + 0][0];
        const float4 d23 = *(const float4*)&SD[k - k0][zh*4 + 2][0];
        HreE[ri][0] = fmaf(d01.x, cv, fmaf(d01.y, sv, HreE[ri][0]));
        HreE[ri][1] = fmaf(d01.z, cv, fmaf(d01.w, sv, HreE[ri][1]));
        HreE[ri][2] = fmaf(d23.x, cv, fmaf(d23.y, sv, HreE[ri][2]));
        HreE[ri][3] = fmaf(d23.z, cv, fmaf(d23.w, sv, HreE[ri][3]));
        float nc = fmaf(cv, dstep_c, -sv*dstep_s);   // forward rotation +4x*theta
        float ns = fmaf(sv, dstep_c,  cv*dstep_s);
        cv = nc; sv = ns;
      }
    }
    // odd residues r=1,3: Re and Im
    #pragma unroll
    for (int ri = 0; ri < 2; ++ri) {
      const int r = ri*2 + 1;
      const int kst = k0 + ((r - (k0 & 3) + 4) & 3);
      if (kst > k1) continue;
      int mm = (kst * x) % 720;
      float sv, cv; sincosf((float)mm * TH, &sv, &cv);
      #pragma unroll 2
      for (int k = kst; k <= k1; k += 4) {
        const float4 d01 = *(const float4*)&SD[k - k0][zh*4 + 0][0];
        const float4 d23 = *(const float4*)&SD[k - k0][zh*4 + 2][0];
        Hro[ri][0] = fmaf(d01.x, cv, fmaf(d01.y, sv, Hro[ri][0]));
        Hio[ri][0] = fmaf(d01.y, cv, fmaf(-d01.x, sv, Hio[ri][0]));
        Hro[ri][1] = fmaf(d01.z, cv, fmaf(d01.w, sv, Hro[ri][1]));
        Hio[ri][1] = fmaf(d01.w, cv, fmaf(-d01.z, sv, Hio[ri][1]));
        Hro[ri][2] = fmaf(d23.x, cv, fmaf(d23.y, sv, Hro[ri][2]));
        Hio[ri][2] = fmaf(d23.y, cv, fmaf(-d23.x, sv, Hio[ri][2]));
        Hro[ri][3] = fmaf(d23.z, cv, fmaf(d23.w, sv, Hro[ri][3]));
        Hio[ri][3] = fmaf(d23.w, cv, fmaf(-d23.z, sv, Hio[ri][3]));
        float nc = fmaf(cv, dstep_c, -sv*dstep_s);   // forward rotation +4x*theta
        float ns = fmaf(sv, dstep_c,  cv*dstep_s);
        cv = nc; sv = ns;
      }
    }

    const float inv = 1.0f/720.0f;
    float o[4][4];
    float4 s0v, s2v, ab01, ab23;
    if (!keep) {
      s0v  = *(const float4*)&S0[x][zh*4];
      s2v  = *(const float4*)&S2[x][zh*4];
      ab01 = *(const float4*)&AB[x][zh*4+0][0];
      ab23 = *(const float4*)&AB[x][zh*4+2][0];
    }
    #pragma unroll
    for (int j = 0; j < 4; ++j) {
      const float h0  = HreE[0][j], h2 = HreE[1][j];
      const float h1r = Hro[0][j],  h1i = Hio[0][j];
      const float h3r = Hro[1][j],  h3i = Hio[1][j];
      float l0 = (h0 + h1r + h2 + h3r) * inv;
      float l1 = (h0 + h1i - h2 - h3i) * inv;
      float l2 = (h0 - h1r + h2 - h3r) * inv;
      float l3 = (h0 - h1i - h2 + h3i) * inv;
      if (!keep) {
        const float s0j = (j==0)?s0v.x:(j==1)?s0v.y:(j==2)?s0v.z:s0v.w;
        const float s2j = (j==0)?s2v.x:(j==1)?s2v.y:(j==2)?s2v.z:s2v.w;
        const float aj  = (j==0)?ab01.x:(j==1)?ab01.z:(j==2)?ab23.x:ab23.z;
        const float bj  = (j==0)?ab01.y:(j==1)?ab01.w:(j==2)?ab23.y:ab23.w;
        const float sp = 0.25f*(s0j + s2j), sm = 0.25f*(s0j - s2j);
        const float q0v = sp + 0.5f*aj, q2v = sp - 0.5f*aj;
        const float q1v = sm + 0.5f*bj, q3v = sm - 0.5f*bj;
        l0 = q0v - l0; l1 = q1v - l1; l2 = q2v - l2; l3 = q3v - l3;
      }
      o[0][j] = fminf(fmaxf(l0, -clipv), clipv);
      o[1][j] = fminf(fmaxf(l1, -clipv), clipv);
      o[2][j] = fminf(fmaxf(l2, -clipv), clipv);
      o[3][j] = fminf(fmaxf(l3, -clipv), clipv);
    }
    #pragma unroll
    for (int j = 0; j < 4; ++j) {
      *(float4*)(base + (size_t)(x + 180*j)*NZ + zh*4) =
          make_float4(o[j][0], o[j][1], o[j][2], o[j][3]);
    }
  }
}

// -------------------- host --------------------
extern "C" void kernel_launch(void* const* d_in, const int* in_sizes, int n_in,
                              void* d_out, int out_size, void* d_ws, size_t ws_size,
                              hipStream_t stream) {
  (void)in_sizes; (void)n_in; (void)d_ws; (void)ws_size; (void)out_size;
  const float* u  = (const float*)d_in[0];
  const float* v  = (const float*)d_in[1];
  const float* T  = (const float*)d_in[2];
  const float* ps = (const float*)d_in[4];
  const float* Rp = (const float*)d_in[6];

  float* out = (float*)d_out;
  float* du  = out;
  float* dv  = out + (size_t)NPTS;
  float* dT  = out + (size_t)2*NPTS;
  float* dq  = out + (size_t)3*NPTS;   // staged as div_h scratch; zeroed in filter
  float* dps = out + (size_t)4*NPTS;

  k_divh<<<NPTS/256, 256, 0, stream>>>(u, v, dq);
  k_tend<<<NCOL/8,   256, 0, stream>>>(u, v, T, ps, Rp, dq, du, dv, dT, dps);
  k_filter4b<<<9360, 384, 0, stream>>>(du, dv, dT, dps, dq);
}

// Round 11
// 558.120 us; speedup vs baseline: 1.1530x; 1.1530x over previous
//
#include <hip/hip_runtime.h>
#include <math.h>

#define NB 2
#define NY 360
#define NX 720
#define NZ 32
#define NPTS (NB*NY*NX*NZ)     // 16,588,800
#define NCOL (NB*NY*NX)        // 518,400

__device__ __forceinline__ int i4(int b,int y,int x,int z){ return (((b*NY)+y)*NX+x)*NZ+z; }
__device__ __forceinline__ int i3(int b,int y,int x){ return ((b*NY)+y)*NX+x; }

#define F_RAD   6371000.0f
#define F_OMEGA 7.292e-5f
#define F_CP    1004.0f
#define F_DLAT  ((float)(M_PI/360.0))                 /* == dlon */
#define F_DYR   ((float)(M_PI/360.0*6371000.0))      /* dlat*RAD */
#define F_HPI   ((float)(M_PI/2.0))
#define TH      ((float)(2.0*M_PI/720.0))

// -------------------- kernel 1: div_h = du/dx + dv/dy --------------------
__global__ __launch_bounds__(256) void k_divh(const float* __restrict__ u,
                                              const float* __restrict__ v,
                                              float* __restrict__ divh) {
  int gid = blockIdx.x*256 + threadIdx.x;          // exact: 64800*256 = NPTS
  int z  = gid & 31;
  int x  = (gid >> 5) % NX;
  int by = gid / (NX*NZ);
  int y  = by % NY;
  int b  = by / NY;
  float lat = -F_HPI + (y+0.5f)*F_DLAT;
  float cl  = cosf(lat);
  float invdx = 0.5f/(F_DLAT*F_RAD*cl);
  int xp = (x==NX-1)?0:x+1, xm = (x==0)?NX-1:x-1;
  float dudx = (u[i4(b,y,xp,z)] - u[i4(b,y,xm,z)]) * invdx;
  float dvdy;
  if (y == 0)          dvdy = (v[i4(b,1,x,z)]    - v[i4(b,0,x,z)])    * (1.0f/F_DYR);
  else if (y == NY-1)  dvdy = (v[i4(b,NY-1,x,z)] - v[i4(b,NY-2,x,z)]) * (1.0f/F_DYR);
  else                 dvdy = (v[i4(b,y+1,x,z)]  - v[i4(b,y-1,x,z)])  * (0.5f/F_DYR);
  divh[gid] = dudx + dvdy;
}

// -------------------- kernel 2: all raw tendencies --------------------
__global__ __launch_bounds__(256) void k_tend(
    const float* __restrict__ u, const float* __restrict__ v,
    const float* __restrict__ T, const float* __restrict__ ps,
    const float* __restrict__ Rp, const float* __restrict__ divh,
    float* __restrict__ du, float* __restrict__ dv,
    float* __restrict__ dT, float* __restrict__ dps) {
  const int tid = threadIdx.x;
  const int z   = tid & 31;
  const int col = blockIdx.x*8 + (tid>>5);         // exact: 64800*8 = NCOL
  const int x = col % NX;
  const int y = (col / NX) % NY;
  const int b = col / (NX*NY);
  const float R = Rp[0];

  const int xp = (x==NX-1)?0:x+1, xm = (x==0)?NX-1:x-1;
  const int ycm = (y>0)? y-1 : 0;
  const int ycp = (y<NY-1)? y+1 : NY-1;
  const bool y0 = (y==0), yN = (y==NY-1);

  const float lat  = -F_HPI + (y+0.5f)*F_DLAT;
  const float cl   = cosf(lat);
  const float fcor = 2.0f*F_OMEGA*sinf(lat);
  const float sx     = F_DLAT*F_RAD*cl;
  const float invdx  = 0.5f/sx;
  const float inv2dy = 0.5f/F_DYR;
  const float inv1dy = 1.0f/F_DYR;
  const float invsx2 = 1.0f/(sx*sx);
  const float invsy2 = 1.0f/(F_DYR*F_DYR);
  const float bk  = (z + 0.5f)/32.0f;
  const float dsv = 1.0f/32.0f;

  const int ic  = i4(b,y,x,z),   ixp = i4(b,y,xp,z), ixm = i4(b,y,xm,z);
  const int iyp = i4(b,ycp,x,z), iym = i4(b,ycm,x,z);

  const float uc=u[ic], uxp=u[ixp], uxm=u[ixm], uyp=u[iyp], uym=u[iym];
  const float vc=v[ic], vxp=v[ixp], vxm=v[ixm], vyp=v[iyp], vym=v[iym];
  const float Tc=T[ic], Txp=T[ixp], Txm=T[ixm], Typ=T[iyp], Tym=T[iym];
  const float Dc=divh[ic], Dxp=divh[ixp], Dxm=divh[ixm], Dyp=divh[iyp], Dym=divh[iym];
  const float psc=ps[i3(b,y,x)],   psxp=ps[i3(b,y,xp)], psxm=ps[i3(b,y,xm)];
  const float psyp=ps[i3(b,ycp,x)], psym=ps[i3(b,ycm,x)];

  auto dfy = [&](float fc_, float fyp_, float fym_) -> float {
    if (y0) return (fyp_ - fc_) * inv1dy;
    if (yN) return (fc_ - fym_) * inv1dy;
    return (fyp_ - fym_) * inv2dy;
  };
  auto lap = [&](float fc_, float fxp_, float fxm_, float fyp_, float fym_) -> float {
    float d2x = (fxp_ + fxm_ - 2.0f*fc_) * invsx2;
    float d2y = (y0||yN) ? 0.0f : (fyp_ + fym_ - 2.0f*fc_) * invsy2;
    return d2x + d2y;
  };
  auto sufscan = [&](float vv) -> float {   // vv[z] = sum_{j>=z}
    #pragma unroll
    for (int d=1; d<32; d<<=1) { float t = __shfl_down(vv, d, 32); if (z+d<32) vv += t; }
    return vv;
  };
  auto prescan = [&](float vv) -> float {   // vv[z] = sum_{j<=z}
    #pragma unroll
    for (int d=1; d<32; d<<=1) { float t = __shfl_up(vv, d, 32); if (z>=d) vv += t; }
    return vv;
  };
  auto vg = [&](float fc_) -> float {       // d/dsigma
    float fzp = __shfl_down(fc_,1,32), fzm = __shfl_up(fc_,1,32);
    if (z==0)  return (fzp - fc_) * 32.0f;
    if (z==31) return (fc_ - fzm) * 32.0f;
    return (fzp - fzm) * 16.0f;
  };

  const float rz = dsv / bk;
  const float phic  = sufscan(R*Tc*rz);
  const float phixp = sufscan(R*Txp*rz);
  const float phixm = sufscan(R*Txm*rz);
  const float phiyp = sufscan(R*Typ*rz);
  const float phiym = sufscan(R*Tym*rz);

  const float dudx = (uxp-uxm)*invdx, dvdx = (vxp-vxm)*invdx, dTdx = (Txp-Txm)*invdx;
  const float dphidx = (phixp-phixm)*invdx;
  const float dudy = dfy(uc,uyp,uym), dvdy_ = dfy(vc,vyp,vym), dTdy = dfy(Tc,Typ,Tym);
  const float dphidy = dfy(phic,phiyp,phiym);
  const float dpsdx = (psxp-psxm)*invdx, dpsdy = dfy(psc,psyp,psym);
  const float gdivx = (Dxp-Dxm)*invdx,  gdivy = dfy(Dc,Dyp,Dym);

  const float mass = Dc*psc + uc*dpsdx + vc*dpsdy;
  float Ipre = prescan(mass) * dsv;
  const float Itot = __shfl(Ipre, 31, 32);
  const float sigd = (bk*Itot - Ipre) / (psc + 1e-8f);

  const float vgu = vg(uc), vgv = vg(vc), vgT = vg(Tc);

  const float pfac = R*Tc*bk/(bk*psc + 1e-8f);
  const float pgfu = -dphidx - pfac*dpsdx;
  const float pgfv = -dphidy - pfac*dpsdy;
  const float cf2  = fmaxf(cl*cl, 0.01f);
  const float nudiv = 500000.0f*cf2, nuh = 100000.0f*cf2;
  const float lapu = lap(uc,uxp,uxm,uyp,uym);
  const float lapv = lap(vc,vxp,vxm,vyp,vym);
  const float lapT = lap(Tc,Txp,Txm,Typ,Tym);
  const float adiab = R*Tc/(bk*psc*F_CP + 1e-8f) * (sigd*psc);

  float dut = -(uc*dudx + vc*dudy)  - sigd*vgu + fcor*vc + pgfu + nuh*lapu - 1e-5f*uc + nudiv*gdivx;
  float dvt = -(uc*dvdx + vc*dvdy_) - sigd*vgv - fcor*uc + pgfv + nuh*lapv - 1e-5f*vc + nudiv*gdivy;
  float dTt = -(uc*dTdx + vc*dTdy)  - sigd*vgT + adiab + nuh*lapT;

  du[ic] = dut; dv[ic] = dvt; dT[ic] = dTt;
  if (z == 0) dps[i3(b,y,x)] = -Itot;
}

// -------------------- polar filter helpers --------------------
__device__ __forceinline__ void filter_band(int y, int& k0, int& k1, bool& keepmode) {
  float lat = -F_HPI + (y+0.5f)*F_DLAT;
  float cut = fmaxf(360.0f*cosf(lat), 1.0f);
  int M = (int)floorf(cut);
  keepmode = (M <= 179);
  k0 = keepmode ? 0 : (M+1);
  k1 = keepmode ? M : 360;
}

// analysis inner-loop steps (R9 form — best measured filter)
#define EVEN_STEP { \
  const float4 a  = *(const float4*)(Sp + i*8); \
  const float4 b4 = *(const float4*)(Sp + i*8 + 4); \
  ac[0]=fmaf(a.x ,c,ac[0]); as[0]=fmaf(a.x ,s,as[0]); \
  ac[1]=fmaf(a.y ,c,ac[1]); as[1]=fmaf(a.y ,s,as[1]); \
  ac[2]=fmaf(a.z ,c,ac[2]); as[2]=fmaf(a.z ,s,as[2]); \
  ac[3]=fmaf(a.w ,c,ac[3]); as[3]=fmaf(a.w ,s,as[3]); \
  ac[4]=fmaf(b4.x,c,ac[4]); as[4]=fmaf(b4.x,s,as[4]); \
  ac[5]=fmaf(b4.y,c,ac[5]); as[5]=fmaf(b4.y,s,as[5]); \
  ac[6]=fmaf(b4.z,c,ac[6]); as[6]=fmaf(b4.z,s,as[6]); \
  ac[7]=fmaf(b4.w,c,ac[7]); as[7]=fmaf(b4.w,s,as[7]); \
  const float nc = fmaf(c, dc, -s*ds); \
  s = fmaf(s, dc, c*ds); c = nc; }

#define ODD_STEP { \
  const float4 p0 = *(const float4*)(Ap + i*16); \
  const float4 p1 = *(const float4*)(Ap + i*16 + 4); \
  const float4 p2 = *(const float4*)(Ap + i*16 + 8); \
  const float4 p3 = *(const float4*)(Ap + i*16 + 12); \
  const float sgc = sg*c, sgs = sg*s; \
  ac[0]=fmaf(p0.x,c,fmaf(p0.y,-sgs,ac[0])); as[0]=fmaf(p0.x,s,fmaf(p0.y,sgc,as[0])); \
  ac[1]=fmaf(p0.z,c,fmaf(p0.w,-sgs,ac[1])); as[1]=fmaf(p0.z,s,fmaf(p0.w,sgc,as[1])); \
  ac[2]=fmaf(p1.x,c,fmaf(p1.y,-sgs,ac[2])); as[2]=fmaf(p1.x,s,fmaf(p1.y,sgc,as[2])); \
  ac[3]=fmaf(p1.z,c,fmaf(p1.w,-sgs,ac[3])); as[3]=fmaf(p1.z,s,fmaf(p1.w,sgc,as[3])); \
  ac[4]=fmaf(p2.x,c,fmaf(p2.y,-sgs,ac[4])); as[4]=fmaf(p2.x,s,fmaf(p2.y,sgc,as[4])); \
  ac[5]=fmaf(p2.z,c,fmaf(p2.w,-sgs,ac[5])); as[5]=fmaf(p2.z,s,fmaf(p2.w,sgc,as[5])); \
  ac[6]=fmaf(p3.x,c,fmaf(p3.y,-sgs,ac[6])); as[6]=fmaf(p3.x,s,fmaf(p3.y,sgc,as[6])); \
  ac[7]=fmaf(p3.z,c,fmaf(p3.w,-sgs,ac[7])); as[7]=fmaf(p3.z,s,fmaf(p3.w,sgc,as[7])); \
  const float nc = fmaf(c, dc, -s*ds); \
  s = fmaf(s, dc, c*ds); c = nc; }

// -------------------- kernel 3: folded-DFT polar filter, all outputs ------
// R9 analysis (one k per slot, 45-x chains, dual mode for cnt>48) + new
// XCD-BALANCED swizzle: hw assigns blockIdx%8 -> XCD. The 4 zq-siblings of
// each (fld,b,y) group stay on ONE XCD (they share 128B z-column cache
// lines: FETCH 404->97MB came from this, not chunking), while GROUPS
// round-robin across XCDs (nk(y) is bimodal, peak ~180 at |lat|=60deg,
// valley ~2 -> chunked mapping gave XCDs ~+-15% work; slowest XCD paced
// the dispatch, OccupancyPercent ~39% vs 75% theoretical).
#define FKMAX 180
__global__ __launch_bounds__(384, 4) void k_filter4b(
    float* __restrict__ du, float* __restrict__ dv, float* __restrict__ dT,
    float* __restrict__ dps, float* __restrict__ dq) {
  __shared__ __align__(16) float smem[8640];   // 34.56 KB

  const int tid = threadIdx.x;
  // grid 9376 = 8 XCDs x 1172 slots; slot s -> (group-local gl=s>>2, zq=s&3);
  // group g = gl*8 + xcd (round-robin); bid = g*4 + zq; 16 pad blocks.
  const int xcd = blockIdx.x & 7;
  const int s   = blockIdx.x >> 3;                 // 0..1171
  const int bid = ((s >> 2) * 8 + xcd) * 4 + (s & 3);
  if (bid >= 9360) return;

  if (bid >= 8640) {
    // ---------------- dpsdt filter path (720 blocks) ----------------
    float*  f  = smem;                          // [720]
    float2* tw = (float2*)(smem + 720);         // [720]
    float*  sc = smem + 720 + 1440;             // [184]
    float*  ss = sc + 184;
    const int row = bid - 8640;                 // 0..719 = b*360+y
    const int y = row % NY;
    float* base = dps + (size_t)row*NX;
    for (int t = tid; t < NX; t += 384) {
      float a = (float)t * TH;
      float sv, cv; sincosf(a, &sv, &cv);
      tw[t] = make_float2(cv, sv);
      f[t] = base[t];
    }
    int k0, k1; bool keepmode;
    filter_band(y, k0, k1, keepmode);
    const int nk = k1 - k0 + 1;
    __syncthreads();
    if (tid < nk) {
      const int k = k0 + tid;
      float ac=0.f, as=0.f; int idx=0;
      for (int xx=0; xx<NX; ++xx) {
        const float fv = f[xx];
        const float2 t2 = tw[idx];
        ac = fmaf(fv, t2.x, ac); as = fmaf(fv, t2.y, as);
        idx += k; if (idx >= NX) idx -= NX;
      }
      sc[tid]=ac; ss[tid]=as;
    }
    __syncthreads();
    if (tid < 360) {
      const int x0 = tid, x1 = tid + 360;
      const int t0 = (x0 * k0) % NX;
      const int t1 = (x1 * k0) % NX;
      float c0 = tw[t0].x, s0 = tw[t0].y;
      float c1 = tw[t1].x, s1 = tw[t1].y;
      const float dc0 = tw[x0].x, dn0 = tw[x0].y;
      const float dc1 = tw[x1].x, dn1 = tw[x1].y;
      float a0 = 0.f, a1 = 0.f;
      for (int kk = 0; kk < nk; ++kk) {
        const int k = k0 + kk;
        const float w = (k==0 || k==360) ? 1.0f : 2.0f;
        a0 = fmaf(sc[kk], w*c0, fmaf(ss[kk], w*s0, a0));
        a1 = fmaf(sc[kk], w*c1, fmaf(ss[kk], w*s1, a1));
        float n0 = c0*dc0 - s0*dn0; s0 = c0*dn0 + s0*dc0; c0 = n0;
        float n1 = c1*dc1 - s1*dn1; s1 = c1*dn1 + s1*dc1; c1 = n1;
      }
      const float inv = 1.0f/720.0f;
      float o0 = keepmode ? a0*inv : f[x0] - a0*inv;
      float o1 = keepmode ? a1*inv : f[x1] - a1*inv;
      o0 = fminf(fmaxf(o0, -0.5f), 0.5f);
      o1 = fminf(fmaxf(o1, -0.5f), 0.5f);
      base[x0] = o0;
      base[x1] = o1;
    }
    return;
  }

  // ---------------- field filter path (8640 blocks) ----------------
  float (*S0)[8]    = (float(*)[8])   smem;           // [180][8]
  float (*S2)[8]    = (float(*)[8])  (smem + 1440);   // [180][8]
  float (*AB)[8][2] = (float(*)[8][2])(smem + 2880);  // [180][8][2]
  float (*SD)[8][2] = (float(*)[8][2])(smem + 5760);  // [180][8][2]

  // fused k_zero: each field block zeroes its 1920-float dq slice
  {
    float4* dqv = (float4*)dq + (size_t)bid * 480;
    const float4 z4 = make_float4(0.f,0.f,0.f,0.f);
    for (int t = tid; t < 480; t += 384) dqv[t] = z4;
  }

  const int zq   = bid & 3;
  const int rest = bid >> 2;
  const int by   = rest % (NB*NY);
  const int fld  = rest / (NB*NY);
  const int y = by % NY, b = by / NY;
  float* fptr = (fld==0)? du : (fld==1)? dv : dT;
  const float clipv = (fld==2)? 0.01f : 0.02f;
  float* base = fptr + ((size_t)(b*NY+y)*NX)*NZ + zq*8;

  int k0, k1; bool keep;
  filter_band(y, k0, k1, keep);

  // ---- load + fold ----
  if (tid < 360) {
    const int x  = tid % 180;
    const int zh = tid / 180;                       // 0/1 -> z offset 4*zh
    const float4 q0 = *(const float4*)(base + (size_t)(x      )*NZ + zh*4);
    const float4 q1 = *(const float4*)(base + (size_t)(x + 180)*NZ + zh*4);
    const float4 q2 = *(const float4*)(base + (size_t)(x + 360)*NZ + zh*4);
    const float4 q3 = *(const float4*)(base + (size_t)(x + 540)*NZ + zh*4);
    float4 s0v, s2v, av, bv;
    s0v.x=q0.x+q1.x+q2.x+q3.x; s2v.x=q0.x-q1.x+q2.x-q3.x; av.x=q0.x-q2.x; bv.x=q1.x-q3.x;
    s0v.y=q0.y+q1.y+q2.y+q3.y; s2v.y=q0.y-q1.y+q2.y-q3.y; av.y=q0.y-q2.y; bv.y=q1.y-q3.y;
    s0v.z=q0.z+q1.z+q2.z+q3.z; s2v.z=q0.z-q1.z+q2.z-q3.z; av.z=q0.z-q2.z; bv.z=q1.z-q3.z;
    s0v.w=q0.w+q1.w+q2.w+q3.w; s2v.w=q0.w-q1.w+q2.w-q3.w; av.w=q0.w-q2.w; bv.w=q1.w-q3.w;
    *(float4*)&S0[x][zh*4] = s0v;
    *(float4*)&S2[x][zh*4] = s2v;
    *(float4*)&AB[x][zh*4+0][0] = make_float4(av.x, bv.x, av.y, bv.y);
    *(float4*)&AB[x][zh*4+2][0] = make_float4(av.z, bv.z, av.w, bv.w);
  }
  __syncthreads();

  // ---- analysis: thread = (ks 0..95, xq 0..3); one k, 8 z ----
  {
    const int xq = tid & 3;
    const int ks = tid >> 2;            // 0..95; waves 0-2 even-class, 3-5 odd
    const bool isodd = (ks >= 48);
    const int slot = isodd ? ks - 48 : ks;
    const int ke0 = k0 + (k0 & 1);      // first even >= k0
    const int ko0 = k0 | 1;             // first odd  >= k0
    const int kbase = isodd ? ko0 : ke0;
    const int cnt   = (k1 >= kbase) ? (((k1 - kbase) >> 1) + 1) : 0;
    const bool dual = (cnt > 48);
    int k, x0; bool act;
    if (dual) { k = kbase + 2*(slot + 48*(xq>>1)); x0 = 90*(xq&1); act = (k <= k1); }
    else      { k = kbase + 2*slot;                x0 = 45*xq;     act = (slot < cnt); }

    float ac[8], as[8];
    #pragma unroll
    for (int j=0;j<8;++j){ ac[j]=0.f; as[j]=0.f; }

    if (act) {
      float dc, ds; sincosf((float)k * TH, &ds, &dc);
      float c, s;   sincosf((float)((k * x0) % 720) * TH, &s, &c);
      if (!isodd) {
        const float* Sp = ((((k & 3) == 0) ? &S0[0][0] : &S2[0][0])) + x0*8;
        if (dual) {
          #pragma unroll 5
          for (int i = 0; i < 90; ++i) EVEN_STEP
        } else {
          #pragma unroll 5
          for (int i = 0; i < 45; ++i) EVEN_STEP
        }
      } else {
        const float sg = ((k & 3) == 1) ? 1.0f : -1.0f;
        const float* Ap = &AB[x0][0][0];
        if (dual) {
          #pragma unroll 3
          for (int i = 0; i < 90; ++i) ODD_STEP
        } else {
          #pragma unroll 3
          for (int i = 0; i < 45; ++i) ODD_STEP
        }
      }
    }
    // combine partial sums over the 4-lane xq group
    #pragma unroll
    for (int j=0;j<8;++j){
      ac[j] += __shfl_xor(ac[j], 1);
      as[j] += __shfl_xor(as[j], 1);
    }
    if (!dual) {
      #pragma unroll
      for (int j=0;j<8;++j){
        ac[j] += __shfl_xor(ac[j], 2);
        as[j] += __shfl_xor(as[j], 2);
      }
    }
    if (act && ((xq & (dual ? 1 : 3)) == 0)) {
      const float w = (k==0 || k==360) ? 1.0f : 2.0f;
      const int r = k - k0;
      *(float4*)&SD[r][0][0] = make_float4(w*ac[0], w*as[0], w*ac[1], w*as[1]);
      *(float4*)&SD[r][2][0] = make_float4(w*ac[2], w*as[2], w*ac[3], w*as[3]);
      *(float4*)&SD[r][4][0] = make_float4(w*ac[4], w*as[4], w*ac[5], w*as[5]);
      *(float4*)&SD[r][6][0] = make_float4(w*ac[6], w*as[6], w*ac[7], w*as[7]);
    }
  }
  __syncthreads();

  // ---- synthesis: thread = (x' 0..179, z-half 0..1), 4 z each ----
  if (tid < 360) {
    const int x  = tid % 180;
    const int zh = tid / 180;
    float HreE[2][4]; float Hro[2][4]; float Hio[2][4];
    #pragma unroll
    for (int i = 0; i < 2; ++i)
      #pragma unroll
      for (int j = 0; j < 4; ++j) { HreE[i][j]=0.f; Hro[i][j]=0.f; Hio[i][j]=0.f; }

    const int m4 = (4*x) % 720;
    float dstep_s, dstep_c; sincosf((float)m4 * TH, &dstep_s, &dstep_c);

    // even residues r=0,2: only Re needed
    #pragma unroll
    for (int ri = 0; ri < 2; ++ri) {
      const int r = ri*2;
      const int kst = k0 + ((r - (k0 & 3) + 4) & 3);
      if (kst > k1) continue;
      int mm = (kst * x) % 720;
      float sv, cv; sincosf((float)mm * TH, &sv, &cv);
      #pragma unroll 2
      for (int k = kst; k <= k1; k += 4) {
        const float4 d01 = *(const float4*)&SD[k - k0][zh*4 + 0][0];
        const float4 d23 = *(const float4*)&SD[k - k0][zh*4 + 2][0];
        HreE[ri][0] = fmaf(d01.x, cv, fmaf(d01.y, sv, HreE[ri][0]));
        HreE[ri][1] = fmaf(d01.z, cv, fmaf(d01.w, sv, HreE[ri][1]));
        HreE[ri][2] = fmaf(d23.x, cv, fmaf(d23.y, sv, HreE[ri][2]));
        HreE[ri][3] = fmaf(d23.z, cv, fmaf(d23.w, sv, HreE[ri][3]));
        float nc = fmaf(cv, dstep_c, -sv*dstep_s);   // forward rotation +4x*theta
        float ns = fmaf(sv, dstep_c,  cv*dstep_s);
        cv = nc; sv = ns;
      }
    }
    // odd residues r=1,3: Re and Im
    #pragma unroll
    for (int ri = 0; ri < 2; ++ri) {
      const int r = ri*2 + 1;
      const int kst = k0 + ((r - (k0 & 3) + 4) & 3);
      if (kst > k1) continue;
      int mm = (kst * x) % 720;
      float sv, cv; sincosf((float)mm * TH, &sv, &cv);
      #pragma unroll 2
      for (int k = kst; k <= k1; k += 4) {
        const float4 d01 = *(const float4*)&SD[k - k0][zh*4 + 0][0];
        const float4 d23 = *(const float4*)&SD[k - k0][zh*4 + 2][0];
        Hro[ri][0] = fmaf(d01.x, cv, fmaf(d01.y, sv, Hro[ri][0]));
        Hio[ri][0] = fmaf(d01.y, cv, fmaf(-d01.x, sv, Hio[ri][0]));
        Hro[ri][1] = fmaf(d01.z, cv, fmaf(d01.w, sv, Hro[ri][1]));
        Hio[ri][1] = fmaf(d01.w, cv, fmaf(-d01.z, sv, Hio[ri][1]));
        Hro[ri][2] = fmaf(d23.x, cv, fmaf(d23.y, sv, Hro[ri][2]));
        Hio[ri][2] = fmaf(d23.y, cv, fmaf(-d23.x, sv, Hio[ri][2]));
        Hro[ri][3] = fmaf(d23.z, cv, fmaf(d23.w, sv, Hro[ri][3]));
        Hio[ri][3] = fmaf(d23.w, cv, fmaf(-d23.z, sv, Hio[ri][3]));
        float nc = fmaf(cv, dstep_c, -sv*dstep_s);   // forward rotation +4x*theta
        float ns = fmaf(sv, dstep_c,  cv*dstep_s);
        cv = nc; sv = ns;
      }
    }

    const float inv = 1.0f/720.0f;
    float o[4][4];
    float4 s0v, s2v, ab01, ab23;
    if (!keep) {
      s0v  = *(const float4*)&S0[x][zh*4];
      s2v  = *(const float4*)&S2[x][zh*4];
      ab01 = *(const float4*)&AB[x][zh*4+0][0];
      ab23 = *(const float4*)&AB[x][zh*4+2][0];
    }
    #pragma unroll
    for (int j = 0; j < 4; ++j) {
      const float h0  = HreE[0][j], h2 = HreE[1][j];
      const float h1r = Hro[0][j],  h1i = Hio[0][j];
      const float h3r = Hro[1][j],  h3i = Hio[1][j];
      float l0 = (h0 + h1r + h2 + h3r) * inv;
      float l1 = (h0 + h1i - h2 - h3i) * inv;
      float l2 = (h0 - h1r + h2 - h3r) * inv;
      float l3 = (h0 - h1i - h2 + h3i) * inv;
      if (!keep) {
        const float s0j = (j==0)?s0v.x:(j==1)?s0v.y:(j==2)?s0v.z:s0v.w;
        const float s2j = (j==0)?s2v.x:(j==1)?s2v.y:(j==2)?s2v.z:s2v.w;
        const float aj  = (j==0)?ab01.x:(j==1)?ab01.z:(j==2)?ab23.x:ab23.z;
        const float bj  = (j==0)?ab01.y:(j==1)?ab01.w:(j==2)?ab23.y:ab23.w;
        const float sp = 0.25f*(s0j + s2j), sm = 0.25f*(s0j - s2j);
        const float q0v = sp + 0.5f*aj, q2v = sp - 0.5f*aj;
        const float q1v = sm + 0.5f*bj, q3v = sm - 0.5f*bj;
        l0 = q0v - l0; l1 = q1v - l1; l2 = q2v - l2; l3 = q3v - l3;
      }
      o[0][j] = fminf(fmaxf(l0, -clipv), clipv);
      o[1][j] = fminf(fmaxf(l1, -clipv), clipv);
      o[2][j] = fminf(fmaxf(l2, -clipv), clipv);
      o[3][j] = fminf(fmaxf(l3, -clipv), clipv);
    }
    #pragma unroll
    for (int j = 0; j < 4; ++j) {
      *(float4*)(base + (size_t)(x + 180*j)*NZ + zh*4) =
          make_float4(o[j][0], o[j][1], o[j][2], o[j][3]);
    }
  }
}

// -------------------- host --------------------
extern "C" void kernel_launch(void* const* d_in, const int* in_sizes, int n_in,
                              void* d_out, int out_size, void* d_ws, size_t ws_size,
                              hipStream_t stream) {
  (void)in_sizes; (void)n_in; (void)d_ws; (void)ws_size; (void)out_size;
  const float* u  = (const float*)d_in[0];
  const float* v  = (const float*)d_in[1];
  const float* T  = (const float*)d_in[2];
  const float* ps = (const float*)d_in[4];
  const float* Rp = (const float*)d_in[6];

  float* out = (float*)d_out;
  float* du  = out;
  float* dv  = out + (size_t)NPTS;
  float* dT  = out + (size_t)2*NPTS;
  float* dq  = out + (size_t)3*NPTS;   // staged as div_h scratch; zeroed in filter
  float* dps = out + (size_t)4*NPTS;

  k_divh<<<NPTS/256, 256, 0, stream>>>(u, v, dq);
  k_tend<<<NCOL/8,   256, 0, stream>>>(u, v, T, ps, Rp, dq, du, dv, dT, dps);
  k_filter4b<<<9376, 384, 0, stream>>>(du, dv, dT, dps, dq);
}

// Round 12
// 550.258 us; speedup vs baseline: 1.1695x; 1.0143x over previous
//
#include <hip/hip_runtime.h>
#include <math.h>

#define NB 2
#define NY 360
#define NX 720
#define NZ 32
#define NPTS (NB*NY*NX*NZ)     // 16,588,800
#define NCOL (NB*NY*NX)        // 518,400

__device__ __forceinline__ int i4(int b,int y,int x,int z){ return (((b*NY)+y)*NX+x)*NZ+z; }
__device__ __forceinline__ int i3(int b,int y,int x){ return ((b*NY)+y)*NX+x; }

#define F_RAD   6371000.0f
#define F_OMEGA 7.292e-5f
#define F_CP    1004.0f
#define F_DLAT  ((float)(M_PI/360.0))                 /* == dlon */
#define F_DYR   ((float)(M_PI/360.0*6371000.0))      /* dlat*RAD */
#define F_HPI   ((float)(M_PI/2.0))
#define TH      ((float)(2.0*M_PI/720.0))

// -------------------- kernel 1: div_h = du/dx + dv/dy --------------------
// Chunked XCD swizzle (64800 = 8*8100): each XCD gets a contiguous 90-row
// band -> y-halo rows L2-resident instead of bouncing to L3.
__global__ __launch_bounds__(256) void k_divh(const float* __restrict__ u,
                                              const float* __restrict__ v,
                                              float* __restrict__ divh) {
  const int bswz = (blockIdx.x & 7) * 8100 + (blockIdx.x >> 3);
  int gid = bswz*256 + threadIdx.x;                // exact: 64800*256 = NPTS
  int z  = gid & 31;
  int x  = (gid >> 5) % NX;
  int by = gid / (NX*NZ);
  int y  = by % NY;
  int b  = by / NY;
  float lat = -F_HPI + (y+0.5f)*F_DLAT;
  float cl  = cosf(lat);
  float invdx = 0.5f/(F_DLAT*F_RAD*cl);
  int xp = (x==NX-1)?0:x+1, xm = (x==0)?NX-1:x-1;
  float dudx = (u[i4(b,y,xp,z)] - u[i4(b,y,xm,z)]) * invdx;
  float dvdy;
  if (y == 0)          dvdy = (v[i4(b,1,x,z)]    - v[i4(b,0,x,z)])    * (1.0f/F_DYR);
  else if (y == NY-1)  dvdy = (v[i4(b,NY-1,x,z)] - v[i4(b,NY-2,x,z)]) * (1.0f/F_DYR);
  else                 dvdy = (v[i4(b,y+1,x,z)]  - v[i4(b,y-1,x,z)])  * (0.5f/F_DYR);
  divh[gid] = dudx + dvdy;
}

// -------------------- kernel 2: all raw tendencies --------------------
__global__ __launch_bounds__(256) void k_tend(
    const float* __restrict__ u, const float* __restrict__ v,
    const float* __restrict__ T, const float* __restrict__ ps,
    const float* __restrict__ Rp, const float* __restrict__ divh,
    float* __restrict__ du, float* __restrict__ dv,
    float* __restrict__ dT, float* __restrict__ dps) {
  const int tid = threadIdx.x;
  const int z   = tid & 31;
  const int bswz = (blockIdx.x & 7) * 8100 + (blockIdx.x >> 3);
  const int col = bswz*8 + (tid>>5);               // exact: 64800*8 = NCOL
  const int x = col % NX;
  const int y = (col / NX) % NY;
  const int b = col / (NX*NY);
  const float R = Rp[0];

  const int xp = (x==NX-1)?0:x+1, xm = (x==0)?NX-1:x-1;
  const int ycm = (y>0)? y-1 : 0;
  const int ycp = (y<NY-1)? y+1 : NY-1;
  const bool y0 = (y==0), yN = (y==NY-1);

  const float lat  = -F_HPI + (y+0.5f)*F_DLAT;
  const float cl   = cosf(lat);
  const float fcor = 2.0f*F_OMEGA*sinf(lat);
  const float sx     = F_DLAT*F_RAD*cl;
  const float invdx  = 0.5f/sx;
  const float inv2dy = 0.5f/F_DYR;
  const float inv1dy = 1.0f/F_DYR;
  const float invsx2 = 1.0f/(sx*sx);
  const float invsy2 = 1.0f/(F_DYR*F_DYR);
  const float bk  = (z + 0.5f)/32.0f;
  const float dsv = 1.0f/32.0f;

  const int ic  = i4(b,y,x,z),   ixp = i4(b,y,xp,z), ixm = i4(b,y,xm,z);
  const int iyp = i4(b,ycp,x,z), iym = i4(b,ycm,x,z);

  const float uc=u[ic], uxp=u[ixp], uxm=u[ixm], uyp=u[iyp], uym=u[iym];
  const float vc=v[ic], vxp=v[ixp], vxm=v[ixm], vyp=v[iyp], vym=v[iym];
  const float Tc=T[ic], Txp=T[ixp], Txm=T[ixm], Typ=T[iyp], Tym=T[iym];
  const float Dc=divh[ic], Dxp=divh[ixp], Dxm=divh[ixm], Dyp=divh[iyp], Dym=divh[iym];
  const float psc=ps[i3(b,y,x)],   psxp=ps[i3(b,y,xp)], psxm=ps[i3(b,y,xm)];
  const float psyp=ps[i3(b,ycp,x)], psym=ps[i3(b,ycm,x)];

  auto dfy = [&](float fc_, float fyp_, float fym_) -> float {
    if (y0) return (fyp_ - fc_) * inv1dy;
    if (yN) return (fc_ - fym_) * inv1dy;
    return (fyp_ - fym_) * inv2dy;
  };
  auto lap = [&](float fc_, float fxp_, float fxm_, float fyp_, float fym_) -> float {
    float d2x = (fxp_ + fxm_ - 2.0f*fc_) * invsx2;
    float d2y = (y0||yN) ? 0.0f : (fyp_ + fym_ - 2.0f*fc_) * invsy2;
    return d2x + d2y;
  };
  auto sufscan = [&](float vv) -> float {   // vv[z] = sum_{j>=z}
    #pragma unroll
    for (int d=1; d<32; d<<=1) { float t = __shfl_down(vv, d, 32); if (z+d<32) vv += t; }
    return vv;
  };
  auto prescan = [&](float vv) -> float {   // vv[z] = sum_{j<=z}
    #pragma unroll
    for (int d=1; d<32; d<<=1) { float t = __shfl_up(vv, d, 32); if (z>=d) vv += t; }
    return vv;
  };
  auto vg = [&](float fc_) -> float {       // d/dsigma
    float fzp = __shfl_down(fc_,1,32), fzm = __shfl_up(fc_,1,32);
    if (z==0)  return (fzp - fc_) * 32.0f;
    if (z==31) return (fc_ - fzm) * 32.0f;
    return (fzp - fzm) * 16.0f;
  };

  const float rz = dsv / bk;
  const float phic  = sufscan(R*Tc*rz);
  const float phixp = sufscan(R*Txp*rz);
  const float phixm = sufscan(R*Txm*rz);
  const float phiyp = sufscan(R*Typ*rz);
  const float phiym = sufscan(R*Tym*rz);

  const float dudx = (uxp-uxm)*invdx, dvdx = (vxp-vxm)*invdx, dTdx = (Txp-Txm)*invdx;
  const float dphidx = (phixp-phixm)*invdx;
  const float dudy = dfy(uc,uyp,uym), dvdy_ = dfy(vc,vyp,vym), dTdy = dfy(Tc,Typ,Tym);
  const float dphidy = dfy(phic,phiyp,phiym);
  const float dpsdx = (psxp-psxm)*invdx, dpsdy = dfy(psc,psyp,psym);
  const float gdivx = (Dxp-Dxm)*invdx,  gdivy = dfy(Dc,Dyp,Dym);

  const float mass = Dc*psc + uc*dpsdx + vc*dpsdy;
  float Ipre = prescan(mass) * dsv;
  const float Itot = __shfl(Ipre, 31, 32);
  const float sigd = (bk*Itot - Ipre) / (psc + 1e-8f);

  const float vgu = vg(uc), vgv = vg(vc), vgT = vg(Tc);

  const float pfac = R*Tc*bk/(bk*psc + 1e-8f);
  const float pgfu = -dphidx - pfac*dpsdx;
  const float pgfv = -dphidy - pfac*dpsdy;
  const float cf2  = fmaxf(cl*cl, 0.01f);
  const float nudiv = 500000.0f*cf2, nuh = 100000.0f*cf2;
  const float lapu = lap(uc,uxp,uxm,uyp,uym);
  const float lapv = lap(vc,vxp,vxm,vyp,vym);
  const float lapT = lap(Tc,Txp,Txm,Typ,Tym);
  const float adiab = R*Tc/(bk*psc*F_CP + 1e-8f) * (sigd*psc);

  float dut = -(uc*dudx + vc*dudy)  - sigd*vgu + fcor*vc + pgfu + nuh*lapu - 1e-5f*uc + nudiv*gdivx;
  float dvt = -(uc*dvdx + vc*dvdy_) - sigd*vgv - fcor*uc + pgfv + nuh*lapv - 1e-5f*vc + nudiv*gdivy;
  float dTt = -(uc*dTdx + vc*dTdy)  - sigd*vgT + adiab + nuh*lapT;

  du[ic] = dut; dv[ic] = dvt; dT[ic] = dTt;
  if (z == 0) dps[i3(b,y,x)] = -Itot;
}

// -------------------- polar filter helpers --------------------
__device__ __forceinline__ void filter_band(int y, int& k0, int& k1, bool& keepmode) {
  float lat = -F_HPI + (y+0.5f)*F_DLAT;
  float cut = fmaxf(360.0f*cosf(lat), 1.0f);
  int M = (int)floorf(cut);
  keepmode = (M <= 179);
  k0 = keepmode ? 0 : (M+1);
  k1 = keepmode ? M : 360;
}

// analysis inner-loop steps (R9 form — best measured filter)
#define EVEN_STEP { \
  const float4 a  = *(const float4*)(Sp + i*8); \
  const float4 b4 = *(const float4*)(Sp + i*8 + 4); \
  ac[0]=fmaf(a.x ,c,ac[0]); as[0]=fmaf(a.x ,s,as[0]); \
  ac[1]=fmaf(a.y ,c,ac[1]); as[1]=fmaf(a.y ,s,as[1]); \
  ac[2]=fmaf(a.z ,c,ac[2]); as[2]=fmaf(a.z ,s,as[2]); \
  ac[3]=fmaf(a.w ,c,ac[3]); as[3]=fmaf(a.w ,s,as[3]); \
  ac[4]=fmaf(b4.x,c,ac[4]); as[4]=fmaf(b4.x,s,as[4]); \
  ac[5]=fmaf(b4.y,c,ac[5]); as[5]=fmaf(b4.y,s,as[5]); \
  ac[6]=fmaf(b4.z,c,ac[6]); as[6]=fmaf(b4.z,s,as[6]); \
  ac[7]=fmaf(b4.w,c,ac[7]); as[7]=fmaf(b4.w,s,as[7]); \
  const float nc = fmaf(c, dc, -s*ds); \
  s = fmaf(s, dc, c*ds); c = nc; }

#define ODD_STEP { \
  const float4 p0 = *(const float4*)(Ap + i*16); \
  const float4 p1 = *(const float4*)(Ap + i*16 + 4); \
  const float4 p2 = *(const float4*)(Ap + i*16 + 8); \
  const float4 p3 = *(const float4*)(Ap + i*16 + 12); \
  const float sgc = sg*c, sgs = sg*s; \
  ac[0]=fmaf(p0.x,c,fmaf(p0.y,-sgs,ac[0])); as[0]=fmaf(p0.x,s,fmaf(p0.y,sgc,as[0])); \
  ac[1]=fmaf(p0.z,c,fmaf(p0.w,-sgs,ac[1])); as[1]=fmaf(p0.z,s,fmaf(p0.w,sgc,as[1])); \
  ac[2]=fmaf(p1.x,c,fmaf(p1.y,-sgs,ac[2])); as[2]=fmaf(p1.x,s,fmaf(p1.y,sgc,as[2])); \
  ac[3]=fmaf(p1.z,c,fmaf(p1.w,-sgs,ac[3])); as[3]=fmaf(p1.z,s,fmaf(p1.w,sgc,as[3])); \
  ac[4]=fmaf(p2.x,c,fmaf(p2.y,-sgs,ac[4])); as[4]=fmaf(p2.x,s,fmaf(p2.y,sgc,as[4])); \
  ac[5]=fmaf(p2.z,c,fmaf(p2.w,-sgs,ac[5])); as[5]=fmaf(p2.z,s,fmaf(p2.w,sgc,as[5])); \
  ac[6]=fmaf(p3.x,c,fmaf(p3.y,-sgs,ac[6])); as[6]=fmaf(p3.x,s,fmaf(p3.y,sgc,as[6])); \
  ac[7]=fmaf(p3.z,c,fmaf(p3.w,-sgs,ac[7])); as[7]=fmaf(p3.z,s,fmaf(p3.w,sgc,as[7])); \
  const float nc = fmaf(c, dc, -s*ds); \
  s = fmaf(s, dc, c*ds); c = nc; }

// -------------------- kernel 3: folded-DFT polar filter, all outputs ------
// R11 structure (unchanged): XCD-balanced swizzle, zq-siblings co-located,
// R9 analysis, fused dpsdt path + dq zeroing.
#define FKMAX 180
__global__ __launch_bounds__(384, 4) void k_filter4b(
    float* __restrict__ du, float* __restrict__ dv, float* __restrict__ dT,
    float* __restrict__ dps, float* __restrict__ dq) {
  __shared__ __align__(16) float smem[8640];   // 34.56 KB

  const int tid = threadIdx.x;
  // grid 9376 = 8 XCDs x 1172 slots; slot s -> (group-local gl=s>>2, zq=s&3);
  // group g = gl*8 + xcd (round-robin); bid = g*4 + zq; 16 pad blocks.
  const int xcd = blockIdx.x & 7;
  const int s   = blockIdx.x >> 3;                 // 0..1171
  const int bid = ((s >> 2) * 8 + xcd) * 4 + (s & 3);
  if (bid >= 9360) return;

  if (bid >= 8640) {
    // ---------------- dpsdt filter path (720 blocks) ----------------
    float*  f  = smem;                          // [720]
    float2* tw = (float2*)(smem + 720);         // [720]
    float*  sc = smem + 720 + 1440;             // [184]
    float*  ss = sc + 184;
    const int row = bid - 8640;                 // 0..719 = b*360+y
    const int y = row % NY;
    float* base = dps + (size_t)row*NX;
    for (int t = tid; t < NX; t += 384) {
      float a = (float)t * TH;
      float sv, cv; sincosf(a, &sv, &cv);
      tw[t] = make_float2(cv, sv);
      f[t] = base[t];
    }
    int k0, k1; bool keepmode;
    filter_band(y, k0, k1, keepmode);
    const int nk = k1 - k0 + 1;
    __syncthreads();
    if (tid < nk) {
      const int k = k0 + tid;
      float ac=0.f, as=0.f; int idx=0;
      for (int xx=0; xx<NX; ++xx) {
        const float fv = f[xx];
        const float2 t2 = tw[idx];
        ac = fmaf(fv, t2.x, ac); as = fmaf(fv, t2.y, as);
        idx += k; if (idx >= NX) idx -= NX;
      }
      sc[tid]=ac; ss[tid]=as;
    }
    __syncthreads();
    if (tid < 360) {
      const int x0 = tid, x1 = tid + 360;
      const int t0 = (x0 * k0) % NX;
      const int t1 = (x1 * k0) % NX;
      float c0 = tw[t0].x, s0 = tw[t0].y;
      float c1 = tw[t1].x, s1 = tw[t1].y;
      const float dc0 = tw[x0].x, dn0 = tw[x0].y;
      const float dc1 = tw[x1].x, dn1 = tw[x1].y;
      float a0 = 0.f, a1 = 0.f;
      for (int kk = 0; kk < nk; ++kk) {
        const int k = k0 + kk;
        const float w = (k==0 || k==360) ? 1.0f : 2.0f;
        a0 = fmaf(sc[kk], w*c0, fmaf(ss[kk], w*s0, a0));
        a1 = fmaf(sc[kk], w*c1, fmaf(ss[kk], w*s1, a1));
        float n0 = c0*dc0 - s0*dn0; s0 = c0*dn0 + s0*dc0; c0 = n0;
        float n1 = c1*dc1 - s1*dn1; s1 = c1*dn1 + s1*dc1; c1 = n1;
      }
      const float inv = 1.0f/720.0f;
      float o0 = keepmode ? a0*inv : f[x0] - a0*inv;
      float o1 = keepmode ? a1*inv : f[x1] - a1*inv;
      o0 = fminf(fmaxf(o0, -0.5f), 0.5f);
      o1 = fminf(fmaxf(o1, -0.5f), 0.5f);
      base[x0] = o0;
      base[x1] = o1;
    }
    return;
  }

  // ---------------- field filter path (8640 blocks) ----------------
  float (*S0)[8]    = (float(*)[8])   smem;           // [180][8]
  float (*S2)[8]    = (float(*)[8])  (smem + 1440);   // [180][8]
  float (*AB)[8][2] = (float(*)[8][2])(smem + 2880);  // [180][8][2]
  float (*SD)[8][2] = (float(*)[8][2])(smem + 5760);  // [180][8][2]

  // fused k_zero: each field block zeroes its 1920-float dq slice
  {
    float4* dqv = (float4*)dq + (size_t)bid * 480;
    const float4 z4 = make_float4(0.f,0.f,0.f,0.f);
    for (int t = tid; t < 480; t += 384) dqv[t] = z4;
  }

  const int zq   = bid & 3;
  const int rest = bid >> 2;
  const int by   = rest % (NB*NY);
  const int fld  = rest / (NB*NY);
  const int y = by % NY, b = by / NY;
  float* fptr = (fld==0)? du : (fld==1)? dv : dT;
  const float clipv = (fld==2)? 0.01f : 0.02f;
  float* base = fptr + ((size_t)(b*NY+y)*NX)*NZ + zq*8;

  int k0, k1; bool keep;
  filter_band(y, k0, k1, keep);

  // ---- load + fold ----
  if (tid < 360) {
    const int x  = tid % 180;
    const int zh = tid / 180;                       // 0/1 -> z offset 4*zh
    const float4 q0 = *(const float4*)(base + (size_t)(x      )*NZ + zh*4);
    const float4 q1 = *(const float4*)(base + (size_t)(x + 180)*NZ + zh*4);
    const float4 q2 = *(const float4*)(base + (size_t)(x + 360)*NZ + zh*4);
    const float4 q3 = *(const float4*)(base + (size_t)(x + 540)*NZ + zh*4);
    float4 s0v, s2v, av, bv;
    s0v.x=q0.x+q1.x+q2.x+q3.x; s2v.x=q0.x-q1.x+q2.x-q3.x; av.x=q0.x-q2.x; bv.x=q1.x-q3.x;
    s0v.y=q0.y+q1.y+q2.y+q3.y; s2v.y=q0.y-q1.y+q2.y-q3.y; av.y=q0.y-q2.y; bv.y=q1.y-q3.y;
    s0v.z=q0.z+q1.z+q2.z+q3.z; s2v.z=q0.z-q1.z+q2.z-q3.z; av.z=q0.z-q2.z; bv.z=q1.z-q3.z;
    s0v.w=q0.w+q1.w+q2.w+q3.w; s2v.w=q0.w-q1.w+q2.w-q3.w; av.w=q0.w-q2.w; bv.w=q1.w-q3.w;
    *(float4*)&S0[x][zh*4] = s0v;
    *(float4*)&S2[x][zh*4] = s2v;
    *(float4*)&AB[x][zh*4+0][0] = make_float4(av.x, bv.x, av.y, bv.y);
    *(float4*)&AB[x][zh*4+2][0] = make_float4(av.z, bv.z, av.w, bv.w);
  }
  __syncthreads();

  // ---- analysis: thread = (ks 0..95, xq 0..3); one k, 8 z ----
  {
    const int xq = tid & 3;
    const int ks = tid >> 2;            // 0..95; waves 0-2 even-class, 3-5 odd
    const bool isodd = (ks >= 48);
    const int slot = isodd ? ks - 48 : ks;
    const int ke0 = k0 + (k0 & 1);      // first even >= k0
    const int ko0 = k0 | 1;             // first odd  >= k0
    const int kbase = isodd ? ko0 : ke0;
    const int cnt   = (k1 >= kbase) ? (((k1 - kbase) >> 1) + 1) : 0;
    const bool dual = (cnt > 48);
    int k, x0; bool act;
    if (dual) { k = kbase + 2*(slot + 48*(xq>>1)); x0 = 90*(xq&1); act = (k <= k1); }
    else      { k = kbase + 2*slot;                x0 = 45*xq;     act = (slot < cnt); }

    float ac[8], as[8];
    #pragma unroll
    for (int j=0;j<8;++j){ ac[j]=0.f; as[j]=0.f; }

    if (act) {
      float dc, ds; sincosf((float)k * TH, &ds, &dc);
      float c, s;   sincosf((float)((k * x0) % 720) * TH, &s, &c);
      if (!isodd) {
        const float* Sp = ((((k & 3) == 0) ? &S0[0][0] : &S2[0][0])) + x0*8;
        if (dual) {
          #pragma unroll 5
          for (int i = 0; i < 90; ++i) EVEN_STEP
        } else {
          #pragma unroll 5
          for (int i = 0; i < 45; ++i) EVEN_STEP
        }
      } else {
        const float sg = ((k & 3) == 1) ? 1.0f : -1.0f;
        const float* Ap = &AB[x0][0][0];
        if (dual) {
          #pragma unroll 3
          for (int i = 0; i < 90; ++i) ODD_STEP
        } else {
          #pragma unroll 3
          for (int i = 0; i < 45; ++i) ODD_STEP
        }
      }
    }
    // combine partial sums over the 4-lane xq group
    #pragma unroll
    for (int j=0;j<8;++j){
      ac[j] += __shfl_xor(ac[j], 1);
      as[j] += __shfl_xor(as[j], 1);
    }
    if (!dual) {
      #pragma unroll
      for (int j=0;j<8;++j){
        ac[j] += __shfl_xor(ac[j], 2);
        as[j] += __shfl_xor(as[j], 2);
      }
    }
    if (act && ((xq & (dual ? 1 : 3)) == 0)) {
      const float w = (k==0 || k==360) ? 1.0f : 2.0f;
      const int r = k - k0;
      *(float4*)&SD[r][0][0] = make_float4(w*ac[0], w*as[0], w*ac[1], w*as[1]);
      *(float4*)&SD[r][2][0] = make_float4(w*ac[2], w*as[2], w*ac[3], w*as[3]);
      *(float4*)&SD[r][4][0] = make_float4(w*ac[4], w*as[4], w*ac[5], w*as[5]);
      *(float4*)&SD[r][6][0] = make_float4(w*ac[6], w*as[6], w*ac[7], w*as[7]);
    }
  }
  __syncthreads();

  // ---- synthesis: thread = (x' 0..179, z-half 0..1), 4 z each ----
  if (tid < 360) {
    const int x  = tid % 180;
    const int zh = tid / 180;
    float HreE[2][4]; float Hro[2][4]; float Hio[2][4];
    #pragma unroll
    for (int i = 0; i < 2; ++i)
      #pragma unroll
      for (int j = 0; j < 4; ++j) { HreE[i][j]=0.f; Hro[i][j]=0.f; Hio[i][j]=0.f; }

    const int m4 = (4*x) % 720;
    float dstep_s, dstep_c; sincosf((float)m4 * TH, &dstep_s, &dstep_c);

    // even residues r=0,2: only Re needed
    #pragma unroll
    for (int ri = 0; ri < 2; ++ri) {
      const int r = ri*2;
      const int kst = k0 + ((r - (k0 & 3) + 4) & 3);
      if (kst > k1) continue;
      int mm = (kst * x) % 720;
      float sv, cv; sincosf((float)mm * TH, &sv, &cv);
      #pragma unroll 2
      for (int k = kst; k <= k1; k += 4) {
        const float4 d01 = *(const float4*)&SD[k - k0][zh*4 + 0][0];
        const float4 d23 = *(const float4*)&SD[k - k0][zh*4 + 2][0];
        HreE[ri][0] = fmaf(d01.x, cv, fmaf(d01.y, sv, HreE[ri][0]));
        HreE[ri][1] = fmaf(d01.z, cv, fmaf(d01.w, sv, HreE[ri][1]));
        HreE[ri][2] = fmaf(d23.x, cv, fmaf(d23.y, sv, HreE[ri][2]));
        HreE[ri][3] = fmaf(d23.z, cv, fmaf(d23.w, sv, HreE[ri][3]));
        float nc = fmaf(cv, dstep_c, -sv*dstep_s);   // forward rotation +4x*theta
        float ns = fmaf(sv, dstep_c,  cv*dstep_s);
        cv = nc; sv = ns;
      }
    }
    // odd residues r=1,3: Re and Im
    #pragma unroll
    for (int ri = 0; ri < 2; ++ri) {
      const int r = ri*2 + 1;
      const int kst = k0 + ((r - (k0 & 3) + 4) & 3);
      if (kst > k1) continue;
      int mm = (kst * x) % 720;
      float sv, cv; sincosf((float)mm * TH, &sv, &cv);
      #pragma unroll 2
      for (int k = kst; k <= k1; k += 4) {
        const float4 d01 = *(const float4*)&SD[k - k0][zh*4 + 0][0];
        const float4 d23 = *(const float4*)&SD[k - k0][zh*4 + 2][0];
        Hro[ri][0] = fmaf(d01.x, cv, fmaf(d01.y, sv, Hro[ri][0]));
        Hio[ri][0] = fmaf(d01.y, cv, fmaf(-d01.x, sv, Hio[ri][0]));
        Hro[ri][1] = fmaf(d01.z, cv, fmaf(d01.w, sv, Hro[ri][1]));
        Hio[ri][1] = fmaf(d01.w, cv, fmaf(-d01.z, sv, Hio[ri][1]));
        Hro[ri][2] = fmaf(d23.x, cv, fmaf(d23.y, sv, Hro[ri][2]));
        Hio[ri][2] = fmaf(d23.y, cv, fmaf(-d23.x, sv, Hio[ri][2]));
        Hro[ri][3] = fmaf(d23.z, cv, fmaf(d23.w, sv, Hro[ri][3]));
        Hio[ri][3] = fmaf(d23.w, cv, fmaf(-d23.z, sv, Hio[ri][3]));
        float nc = fmaf(cv, dstep_c, -sv*dstep_s);   // forward rotation +4x*theta
        float ns = fmaf(sv, dstep_c,  cv*dstep_s);
        cv = nc; sv = ns;
      }
    }

    const float inv = 1.0f/720.0f;
    float o[4][4];
    float4 s0v, s2v, ab01, ab23;
    if (!keep) {
      s0v  = *(const float4*)&S0[x][zh*4];
      s2v  = *(const float4*)&S2[x][zh*4];
      ab01 = *(const float4*)&AB[x][zh*4+0][0];
      ab23 = *(const float4*)&AB[x][zh*4+2][0];
    }
    #pragma unroll
    for (int j = 0; j < 4; ++j) {
      const float h0  = HreE[0][j], h2 = HreE[1][j];
      const float h1r = Hro[0][j],  h1i = Hio[0][j];
      const float h3r = Hro[1][j],  h3i = Hio[1][j];
      float l0 = (h0 + h1r + h2 + h3r) * inv;
      float l1 = (h0 + h1i - h2 - h3i) * inv;
      float l2 = (h0 - h1r + h2 - h3r) * inv;
      float l3 = (h0 - h1i - h2 + h3i) * inv;
      if (!keep) {
        const float s0j = (j==0)?s0v.x:(j==1)?s0v.y:(j==2)?s0v.z:s0v.w;
        const float s2j = (j==0)?s2v.x:(j==1)?s2v.y:(j==2)?s2v.z:s2v.w;
        const float aj  = (j==0)?ab01.x:(j==1)?ab01.z:(j==2)?ab23.x:ab23.z;
        const float bj  = (j==0)?ab01.y:(j==1)?ab01.w:(j==2)?ab23.y:ab23.w;
        const float sp = 0.25f*(s0j + s2j), sm = 0.25f*(s0j - s2j);
        const float q0v = sp + 0.5f*aj, q2v = sp - 0.5f*aj;
        const float q1v = sm + 0.5f*bj, q3v = sm - 0.5f*bj;
        l0 = q0v - l0; l1 = q1v - l1; l2 = q2v - l2; l3 = q3v - l3;
      }
      o[0][j] = fminf(fmaxf(l0, -clipv), clipv);
      o[1][j] = fminf(fmaxf(l1, -clipv), clipv);
      o[2][j] = fminf(fmaxf(l2, -clipv), clipv);
      o[3][j] = fminf(fmaxf(l3, -clipv), clipv);
    }
    #pragma unroll
    for (int j = 0; j < 4; ++j) {
      *(float4*)(base + (size_t)(x + 180*j)*NZ + zh*4) =
          make_float4(o[j][0], o[j][1], o[j][2], o[j][3]);
    }
  }
}

// -------------------- host --------------------
extern "C" void kernel_launch(void* const* d_in, const int* in_sizes, int n_in,
                              void* d_out, int out_size, void* d_ws, size_t ws_size,
                              hipStream_t stream) {
  (void)in_sizes; (void)n_in; (void)d_ws; (void)ws_size; (void)out_size;
  const float* u  = (const float*)d_in[0];
  const float* v  = (const float*)d_in[1];
  const float* T  = (const float*)d_in[2];
  const float* ps = (const float*)d_in[4];
  const float* Rp = (const float*)d_in[6];

  float* out = (float*)d_out;
  float* du  = out;
  float* dv  = out + (size_t)NPTS;
  float* dT  = out + (size_t)2*NPTS;
  float* dq  = out + (size_t)3*NPTS;   // staged as div_h scratch; zeroed in filter
  float* dps = out + (size_t)4*NPTS;

  k_divh<<<NPTS/256, 256, 0, stream>>>(u, v, dq);
  k_tend<<<NCOL/8,   256, 0, stream>>>(u, v, T, ps, Rp, dq, du, dv, dT, dps);
  k_filter4b<<<9376, 384, 0, stream>>>(du, dv, dT, dps, dq);
}

// Round 13
// 460.086 us; speedup vs baseline: 1.3987x; 1.1960x over previous
//
#include <hip/hip_runtime.h>
#include <math.h>

#define NB 2
#define NY 360
#define NX 720
#define NZ 32
#define NPTS (NB*NY*NX*NZ)     // 16,588,800
#define NCOL (NB*NY*NX)        // 518,400

__device__ __forceinline__ int i4(int b,int y,int x,int z){ return (((b*NY)+y)*NX+x)*NZ+z; }
__device__ __forceinline__ int i3(int b,int y,int x){ return ((b*NY)+y)*NX+x; }

#define F_RAD   6371000.0f
#define F_OMEGA 7.292e-5f
#define F_CP    1004.0f
#define F_DLAT  ((float)(M_PI/360.0))                 /* == dlon */
#define F_DYR   ((float)(M_PI/360.0*6371000.0))      /* dlat*RAD */
#define F_HPI   ((float)(M_PI/2.0))
#define TH      ((float)(2.0*M_PI/720.0))

// -------------------- kernel 1: div_h = du/dx + dv/dy --------------------
__global__ __launch_bounds__(256) void k_divh(const float* __restrict__ u,
                                              const float* __restrict__ v,
                                              float* __restrict__ divh) {
  const int bswz = (blockIdx.x & 7) * 8100 + (blockIdx.x >> 3);
  int gid = bswz*256 + threadIdx.x;                // exact: 64800*256 = NPTS
  int z  = gid & 31;
  int x  = (gid >> 5) % NX;
  int by = gid / (NX*NZ);
  int y  = by % NY;
  int b  = by / NY;
  float lat = -F_HPI + (y+0.5f)*F_DLAT;
  float cl  = cosf(lat);
  float invdx = 0.5f/(F_DLAT*F_RAD*cl);
  int xp = (x==NX-1)?0:x+1, xm = (x==0)?NX-1:x-1;
  float dudx = (u[i4(b,y,xp,z)] - u[i4(b,y,xm,z)]) * invdx;
  float dvdy;
  if (y == 0)          dvdy = (v[i4(b,1,x,z)]    - v[i4(b,0,x,z)])    * (1.0f/F_DYR);
  else if (y == NY-1)  dvdy = (v[i4(b,NY-1,x,z)] - v[i4(b,NY-2,x,z)]) * (1.0f/F_DYR);
  else                 dvdy = (v[i4(b,y+1,x,z)]  - v[i4(b,y-1,x,z)])  * (0.5f/F_DYR);
  divh[gid] = dudx + dvdy;
}

// -------------------- kernel 2: all raw tendencies --------------------
__global__ __launch_bounds__(256) void k_tend(
    const float* __restrict__ u, const float* __restrict__ v,
    const float* __restrict__ T, const float* __restrict__ ps,
    const float* __restrict__ Rp, const float* __restrict__ divh,
    float* __restrict__ du, float* __restrict__ dv,
    float* __restrict__ dT, float* __restrict__ dps) {
  const int tid = threadIdx.x;
  const int z   = tid & 31;
  const int bswz = (blockIdx.x & 7) * 8100 + (blockIdx.x >> 3);
  const int col = bswz*8 + (tid>>5);               // exact: 64800*8 = NCOL
  const int x = col % NX;
  const int y = (col / NX) % NY;
  const int b = col / (NX*NY);
  const float R = Rp[0];

  const int xp = (x==NX-1)?0:x+1, xm = (x==0)?NX-1:x-1;
  const int ycm = (y>0)? y-1 : 0;
  const int ycp = (y<NY-1)? y+1 : NY-1;
  const bool y0 = (y==0), yN = (y==NY-1);

  const float lat  = -F_HPI + (y+0.5f)*F_DLAT;
  const float cl   = cosf(lat);
  const float fcor = 2.0f*F_OMEGA*sinf(lat);
  const float sx     = F_DLAT*F_RAD*cl;
  const float invdx  = 0.5f/sx;
  const float inv2dy = 0.5f/F_DYR;
  const float inv1dy = 1.0f/F_DYR;
  const float invsx2 = 1.0f/(sx*sx);
  const float invsy2 = 1.0f/(F_DYR*F_DYR);
  const float bk  = (z + 0.5f)/32.0f;
  const float dsv = 1.0f/32.0f;

  const int ic  = i4(b,y,x,z),   ixp = i4(b,y,xp,z), ixm = i4(b,y,xm,z);
  const int iyp = i4(b,ycp,x,z), iym = i4(b,ycm,x,z);

  const float uc=u[ic], uxp=u[ixp], uxm=u[ixm], uyp=u[iyp], uym=u[iym];
  const float vc=v[ic], vxp=v[ixp], vxm=v[ixm], vyp=v[iyp], vym=v[iym];
  const float Tc=T[ic], Txp=T[ixp], Txm=T[ixm], Typ=T[iyp], Tym=T[iym];
  const float Dc=divh[ic], Dxp=divh[ixp], Dxm=divh[ixm], Dyp=divh[iyp], Dym=divh[iym];
  const float psc=ps[i3(b,y,x)],   psxp=ps[i3(b,y,xp)], psxm=ps[i3(b,y,xm)];
  const float psyp=ps[i3(b,ycp,x)], psym=ps[i3(b,ycm,x)];

  auto dfy = [&](float fc_, float fyp_, float fym_) -> float {
    if (y0) return (fyp_ - fc_) * inv1dy;
    if (yN) return (fc_ - fym_) * inv1dy;
    return (fyp_ - fym_) * inv2dy;
  };
  auto lap = [&](float fc_, float fxp_, float fxm_, float fyp_, float fym_) -> float {
    float d2x = (fxp_ + fxm_ - 2.0f*fc_) * invsx2;
    float d2y = (y0||yN) ? 0.0f : (fyp_ + fym_ - 2.0f*fc_) * invsy2;
    return d2x + d2y;
  };
  auto sufscan = [&](float vv) -> float {   // vv[z] = sum_{j>=z}
    #pragma unroll
    for (int d=1; d<32; d<<=1) { float t = __shfl_down(vv, d, 32); if (z+d<32) vv += t; }
    return vv;
  };
  auto prescan = [&](float vv) -> float {   // vv[z] = sum_{j<=z}
    #pragma unroll
    for (int d=1; d<32; d<<=1) { float t = __shfl_up(vv, d, 32); if (z>=d) vv += t; }
    return vv;
  };
  auto vg = [&](float fc_) -> float {       // d/dsigma
    float fzp = __shfl_down(fc_,1,32), fzm = __shfl_up(fc_,1,32);
    if (z==0)  return (fzp - fc_) * 32.0f;
    if (z==31) return (fc_ - fzm) * 32.0f;
    return (fzp - fzm) * 16.0f;
  };

  const float rz = dsv / bk;
  const float phic  = sufscan(R*Tc*rz);
  const float phixp = sufscan(R*Txp*rz);
  const float phixm = sufscan(R*Txm*rz);
  const float phiyp = sufscan(R*Typ*rz);
  const float phiym = sufscan(R*Tym*rz);

  const float dudx = (uxp-uxm)*invdx, dvdx = (vxp-vxm)*invdx, dTdx = (Txp-Txm)*invdx;
  const float dphidx = (phixp-phixm)*invdx;
  const float dudy = dfy(uc,uyp,uym), dvdy_ = dfy(vc,vyp,vym), dTdy = dfy(Tc,Typ,Tym);
  const float dphidy = dfy(phic,phiyp,phiym);
  const float dpsdx = (psxp-psxm)*invdx, dpsdy = dfy(psc,psyp,psym);
  const float gdivx = (Dxp-Dxm)*invdx,  gdivy = dfy(Dc,Dyp,Dym);

  const float mass = Dc*psc + uc*dpsdx + vc*dpsdy;
  float Ipre = prescan(mass) * dsv;
  const float Itot = __shfl(Ipre, 31, 32);
  const float sigd = (bk*Itot - Ipre) / (psc + 1e-8f);

  const float vgu = vg(uc), vgv = vg(vc), vgT = vg(Tc);

  const float pfac = R*Tc*bk/(bk*psc + 1e-8f);
  const float pgfu = -dphidx - pfac*dpsdx;
  const float pgfv = -dphidy - pfac*dpsdy;
  const float cf2  = fmaxf(cl*cl, 0.01f);
  const float nudiv = 500000.0f*cf2, nuh = 100000.0f*cf2;
  const float lapu = lap(uc,uxp,uxm,uyp,uym);
  const float lapv = lap(vc,vxp,vxm,vyp,vym);
  const float lapT = lap(Tc,Txp,Txm,Typ,Tym);
  const float adiab = R*Tc/(bk*psc*F_CP + 1e-8f) * (sigd*psc);

  float dut = -(uc*dudx + vc*dudy)  - sigd*vgu + fcor*vc + pgfu + nuh*lapu - 1e-5f*uc + nudiv*gdivx;
  float dvt = -(uc*dvdx + vc*dvdy_) - sigd*vgv - fcor*uc + pgfv + nuh*lapv - 1e-5f*vc + nudiv*gdivy;
  float dTt = -(uc*dTdx + vc*dTdy)  - sigd*vgT + adiab + nuh*lapT;

  du[ic] = dut; dv[ic] = dvt; dT[ic] = dTt;
  if (z == 0) dps[i3(b,y,x)] = -Itot;
}

// -------------------- polar filter helpers --------------------
__device__ __forceinline__ void filter_band(int y, int& k0, int& k1, bool& keepmode) {
  float lat = -F_HPI + (y+0.5f)*F_DLAT;
  float cut = fmaxf(360.0f*cosf(lat), 1.0f);
  int M = (int)floorf(cut);
  keepmode = (M <= 179);
  k0 = keepmode ? 0 : (M+1);
  k1 = keepmode ? M : 360;
}

// -------------------- kernel 3: folded-DFT polar filter, all outputs ------
// Mirror (radix-2) fold on top of the fold-4 DFT: theta*k*180 = (pi/2)k, so
// within each mod-4 residue class the phasor at 180-x is a FIXED rotation of
// the phasor at x (r=0:(c,-s); r=2:(-c,s); r=1:(s,c); r=3:(-s,-c)).
// Analysis: pair-folded arrays over 91 slots (x=0,90 self-slots: mirror:=0).
//   r=0: c-sum uses S0p=g+g', s-sum S0m=g-g'.  r=2: c-sum S2m, s-sum S2p.
//   odd: Q1=A-B', Q2=A'-B, Q3=A'+B, Q4=A+B'; ac+=Q1*c+Q2*(sg*s),
//   as+=Q3*(sg*c)+Q4*s  (sg=+1 r=1, -1 r=3).
// Synthesis: split cos/sin partial sums; mirror output 180-p is a +-
// recombination of the same sums -> 182 threads serve all 360 outputs.
#define FKMAX 180
__global__ __launch_bounds__(384, 4) void k_filter4b(
    float* __restrict__ du, float* __restrict__ dv, float* __restrict__ dT,
    float* __restrict__ dps, float* __restrict__ dq) {
  __shared__ __align__(16) float smem[8704];   // 34.816 KB

  const int tid = threadIdx.x;
  // grid 9376 = 8 XCDs x 1172 slots; zq-siblings same XCD, groups round-robin
  const int xcd = blockIdx.x & 7;
  const int s   = blockIdx.x >> 3;                 // 0..1171
  const int bid = ((s >> 2) * 8 + xcd) * 4 + (s & 3);
  if (bid >= 9360) return;

  if (bid >= 8640) {
    // ---------------- dpsdt filter path (720 blocks) ----------------
    float*  f  = smem;                          // [720]
    float2* tw = (float2*)(smem + 720);         // [720]
    float*  sc = smem + 720 + 1440;             // [184]
    float*  ss = sc + 184;
    const int row = bid - 8640;                 // 0..719 = b*360+y
    const int y = row % NY;
    float* base = dps + (size_t)row*NX;
    for (int t = tid; t < NX; t += 384) {
      float a = (float)t * TH;
      float sv, cv; sincosf(a, &sv, &cv);
      tw[t] = make_float2(cv, sv);
      f[t] = base[t];
    }
    int k0, k1; bool keepmode;
    filter_band(y, k0, k1, keepmode);
    const int nk = k1 - k0 + 1;
    __syncthreads();
    if (tid < nk) {
      const int k = k0 + tid;
      float ac=0.f, as=0.f; int idx=0;
      for (int xx=0; xx<NX; ++xx) {
        const float fv = f[xx];
        const float2 t2 = tw[idx];
        ac = fmaf(fv, t2.x, ac); as = fmaf(fv, t2.y, as);
        idx += k; if (idx >= NX) idx -= NX;
      }
      sc[tid]=ac; ss[tid]=as;
    }
    __syncthreads();
    if (tid < 360) {
      const int x0 = tid, x1 = tid + 360;
      const int t0 = (x0 * k0) % NX;
      const int t1 = (x1 * k0) % NX;
      float c0 = tw[t0].x, s0 = tw[t0].y;
      float c1 = tw[t1].x, s1 = tw[t1].y;
      const float dc0 = tw[x0].x, dn0 = tw[x0].y;
      const float dc1 = tw[x1].x, dn1 = tw[x1].y;
      float a0 = 0.f, a1 = 0.f;
      for (int kk = 0; kk < nk; ++kk) {
        const int k = k0 + kk;
        const float w = (k==0 || k==360) ? 1.0f : 2.0f;
        a0 = fmaf(sc[kk], w*c0, fmaf(ss[kk], w*s0, a0));
        a1 = fmaf(sc[kk], w*c1, fmaf(ss[kk], w*s1, a1));
        float n0 = c0*dc0 - s0*dn0; s0 = c0*dn0 + s0*dc0; c0 = n0;
        float n1 = c1*dc1 - s1*dn1; s1 = c1*dn1 + s1*dc1; c1 = n1;
      }
      const float inv = 1.0f/720.0f;
      float o0 = keepmode ? a0*inv : f[x0] - a0*inv;
      float o1 = keepmode ? a1*inv : f[x1] - a1*inv;
      o0 = fminf(fmaxf(o0, -0.5f), 0.5f);
      o1 = fminf(fmaxf(o1, -0.5f), 0.5f);
      base[x0] = o0;
      base[x1] = o1;
    }
    return;
  }

  // ---------------- field filter path (8640 blocks) ----------------
  float* S0p = smem + 0;       // [91][8]
  float* S0m = smem + 728;
  float* S2p = smem + 1456;
  float* S2m = smem + 2184;
  float* Q1a = smem + 2912;
  float* Q2a = smem + 3640;
  float* Q3a = smem + 4368;
  float* Q4a = smem + 5096;
  float (*SD)[8][2] = (float(*)[8][2])(smem + 5824);  // [180][8][2]

  // fused k_zero: each field block zeroes its 1920-float dq slice
  {
    float4* dqv = (float4*)dq + (size_t)bid * 480;
    const float4 z4 = make_float4(0.f,0.f,0.f,0.f);
    for (int t = tid; t < 480; t += 384) dqv[t] = z4;
  }

  const int zq   = bid & 3;
  const int rest = bid >> 2;
  const int by   = rest % (NB*NY);
  const int fld  = rest / (NB*NY);
  const int y = by % NY, b = by / NY;
  float* fptr = (fld==0)? du : (fld==1)? dv : dT;
  const float clipv = (fld==2)? 0.01f : 0.02f;
  float* base = fptr + ((size_t)(b*NY+y)*NX)*NZ + zq*8;

  int k0, k1; bool keep;
  filter_band(y, k0, k1, keep);

  // ---- load + fold4 + mirror-fold (tid<182: pair-slot p, z-half zh) ----
  if (tid < 182) {
    const int p  = tid % 91;
    const int zh = tid / 91;
    const bool hasm = (p >= 1 && p <= 89);
    const int xm = 180 - p;
    const float4 q0 = *(const float4*)(base + (size_t)(p      )*NZ + zh*4);
    const float4 q1 = *(const float4*)(base + (size_t)(p + 180)*NZ + zh*4);
    const float4 q2 = *(const float4*)(base + (size_t)(p + 360)*NZ + zh*4);
    const float4 q3 = *(const float4*)(base + (size_t)(p + 540)*NZ + zh*4);
    float4 m0 = make_float4(0,0,0,0), m1 = m0, m2 = m0, m3 = m0;
    if (hasm) {
      m0 = *(const float4*)(base + (size_t)(xm      )*NZ + zh*4);
      m1 = *(const float4*)(base + (size_t)(xm + 180)*NZ + zh*4);
      m2 = *(const float4*)(base + (size_t)(xm + 360)*NZ + zh*4);
      m3 = *(const float4*)(base + (size_t)(xm + 540)*NZ + zh*4);
    }
    const int o = p*8 + zh*4;
    #pragma unroll
    for (int j = 0; j < 4; ++j) {
      const float a0 = (j==0)?q0.x:(j==1)?q0.y:(j==2)?q0.z:q0.w;
      const float a1 = (j==0)?q1.x:(j==1)?q1.y:(j==2)?q1.z:q1.w;
      const float a2 = (j==0)?q2.x:(j==1)?q2.y:(j==2)?q2.z:q2.w;
      const float a3 = (j==0)?q3.x:(j==1)?q3.y:(j==2)?q3.z:q3.w;
      const float b0 = (j==0)?m0.x:(j==1)?m0.y:(j==2)?m0.z:m0.w;
      const float b1 = (j==0)?m1.x:(j==1)?m1.y:(j==2)?m1.z:m1.w;
      const float b2 = (j==0)?m2.x:(j==1)?m2.y:(j==2)?m2.z:m2.w;
      const float b3 = (j==0)?m3.x:(j==1)?m3.y:(j==2)?m3.z:m3.w;
      const float s0  = a0+a1+a2+a3, s2  = a0-a1+a2-a3, A  = a0-a2, B  = a1-a3;
      const float s0M = b0+b1+b2+b3, s2M = b0-b1+b2-b3, AM = b0-b2, BM = b1-b3;
      S0p[o+j] = s0 + s0M;  S0m[o+j] = s0 - s0M;
      S2p[o+j] = s2 + s2M;  S2m[o+j] = s2 - s2M;
      Q1a[o+j] = A - BM;    Q2a[o+j] = AM - B;
      Q3a[o+j] = AM + B;    Q4a[o+j] = A + BM;
    }
  }
  __syncthreads();

  // ---- analysis: thread = (ks 0..95, xq 0..3); one k, 8 z, 91 slots ----
  {
    const int xq = tid & 3;
    const int ks = tid >> 2;            // 0..95; waves 0-2 even-class, 3-5 odd
    const bool isodd = (ks >= 48);
    const int slot = isodd ? ks - 48 : ks;
    const int ke0 = k0 + (k0 & 1);      // first even >= k0
    const int ko0 = k0 | 1;             // first odd  >= k0
    const int kbase = isodd ? ko0 : ke0;
    const int cnt   = (k1 >= kbase) ? (((k1 - kbase) >> 1) + 1) : 0;
    const bool dual = (cnt > 48);
    int k, x0, xe; bool act;
    if (dual) { k = kbase + 2*(slot + 48*(xq>>1)); x0 = (xq&1)?46:0; xe = (xq&1)?91:46; act = (k <= k1); }
    else      { k = kbase + 2*slot; x0 = 23*xq; xe = (xq==3)?91:(x0+23); act = (slot < cnt); }

    float ac[8], as[8];
    #pragma unroll
    for (int j=0;j<8;++j){ ac[j]=0.f; as[j]=0.f; }

    if (act) {
      float dc, ds; sincosf((float)k * TH, &ds, &dc);
      float c, s;   sincosf((float)((k * x0) % 720) * TH, &s, &c);
      const int n = xe - x0;
      if (!isodd) {
        const int r = k & 3;
        const float* Pc = ((r == 0) ? S0p : S2m) + x0*8;
        const float* Ps = ((r == 0) ? S0m : S2p) + x0*8;
        #pragma unroll 4
        for (int i = 0; i < n; ++i) {
          const float4 c0 = *(const float4*)(Pc + i*8);
          const float4 c1 = *(const float4*)(Pc + i*8 + 4);
          const float4 s0v = *(const float4*)(Ps + i*8);
          const float4 s1v = *(const float4*)(Ps + i*8 + 4);
          ac[0]=fmaf(c0.x ,c,ac[0]); as[0]=fmaf(s0v.x,s,as[0]);
          ac[1]=fmaf(c0.y ,c,ac[1]); as[1]=fmaf(s0v.y,s,as[1]);
          ac[2]=fmaf(c0.z ,c,ac[2]); as[2]=fmaf(s0v.z,s,as[2]);
          ac[3]=fmaf(c0.w ,c,ac[3]); as[3]=fmaf(s0v.w,s,as[3]);
          ac[4]=fmaf(c1.x ,c,ac[4]); as[4]=fmaf(s1v.x,s,as[4]);
          ac[5]=fmaf(c1.y ,c,ac[5]); as[5]=fmaf(s1v.y,s,as[5]);
          ac[6]=fmaf(c1.z ,c,ac[6]); as[6]=fmaf(s1v.z,s,as[6]);
          ac[7]=fmaf(c1.w ,c,ac[7]); as[7]=fmaf(s1v.w,s,as[7]);
          const float nc = fmaf(c, dc, -s*ds);
          s = fmaf(s, dc, c*ds); c = nc;
        }
      } else {
        const float sg = ((k & 3) == 1) ? 1.0f : -1.0f;
        const float* p1 = Q1a + x0*8; const float* p2 = Q2a + x0*8;
        const float* p3 = Q3a + x0*8; const float* p4 = Q4a + x0*8;
        #pragma unroll 2
        for (int i = 0; i < n; ++i) {
          const float4 u10 = *(const float4*)(p1 + i*8);
          const float4 u11 = *(const float4*)(p1 + i*8 + 4);
          const float4 u20 = *(const float4*)(p2 + i*8);
          const float4 u21 = *(const float4*)(p2 + i*8 + 4);
          const float4 u30 = *(const float4*)(p3 + i*8);
          const float4 u31 = *(const float4*)(p3 + i*8 + 4);
          const float4 u40 = *(const float4*)(p4 + i*8);
          const float4 u41 = *(const float4*)(p4 + i*8 + 4);
          const float svs = sg*s, cvs = sg*c;
          ac[0]=fmaf(u10.x,c,fmaf(u20.x,svs,ac[0])); as[0]=fmaf(u30.x,cvs,fmaf(u40.x,s,as[0]));
          ac[1]=fmaf(u10.y,c,fmaf(u20.y,svs,ac[1])); as[1]=fmaf(u30.y,cvs,fmaf(u40.y,s,as[1]));
          ac[2]=fmaf(u10.z,c,fmaf(u20.z,svs,ac[2])); as[2]=fmaf(u30.z,cvs,fmaf(u40.z,s,as[2]));
          ac[3]=fmaf(u10.w,c,fmaf(u20.w,svs,ac[3])); as[3]=fmaf(u30.w,cvs,fmaf(u40.w,s,as[3]));
          ac[4]=fmaf(u11.x,c,fmaf(u21.x,svs,ac[4])); as[4]=fmaf(u31.x,cvs,fmaf(u41.x,s,as[4]));
          ac[5]=fmaf(u11.y,c,fmaf(u21.y,svs,ac[5])); as[5]=fmaf(u31.y,cvs,fmaf(u41.y,s,as[5]));
          ac[6]=fmaf(u11.z,c,fmaf(u21.z,svs,ac[6])); as[6]=fmaf(u31.z,cvs,fmaf(u41.z,s,as[6]));
          ac[7]=fmaf(u11.w,c,fmaf(u21.w,svs,ac[7])); as[7]=fmaf(u31.w,cvs,fmaf(u41.w,s,as[7]));
          const float nc = fmaf(c, dc, -s*ds);
          s = fmaf(s, dc, c*ds); c = nc;
        }
      }
    }
    // combine partial sums over the 4-lane xq group
    #pragma unroll
    for (int j=0;j<8;++j){
      ac[j] += __shfl_xor(ac[j], 1);
      as[j] += __shfl_xor(as[j], 1);
    }
    if (!dual) {
      #pragma unroll
      for (int j=0;j<8;++j){
        ac[j] += __shfl_xor(ac[j], 2);
        as[j] += __shfl_xor(as[j], 2);
      }
    }
    if (act && ((xq & (dual ? 1 : 3)) == 0)) {
      const float w = (k==0 || k==360) ? 1.0f : 2.0f;
      const int r = k - k0;
      *(float4*)&SD[r][0][0] = make_float4(w*ac[0], w*as[0], w*ac[1], w*as[1]);
      *(float4*)&SD[r][2][0] = make_float4(w*ac[2], w*as[2], w*ac[3], w*as[3]);
      *(float4*)&SD[r][4][0] = make_float4(w*ac[4], w*as[4], w*ac[5], w*as[5]);
      *(float4*)&SD[r][6][0] = make_float4(w*ac[6], w*as[6], w*ac[7], w*as[7]);
    }
  }
  __syncthreads();

  // ---- synthesis: thread = (pair p 0..90, zh 0..1) serves x=p and 180-p ----
  if (tid < 182) {
    const int p  = tid % 91;
    const int zh = tid / 91;
    const bool hasm = (p >= 1 && p <= 89);
    float lx0[4],lx1[4],lx2[4],lx3[4], lm0[4],lm1[4],lm2[4],lm3[4];
    #pragma unroll
    for (int j=0;j<4;++j){ lx0[j]=lx1[j]=lx2[j]=lx3[j]=0.f; lm0[j]=lm1[j]=lm2[j]=lm3[j]=0.f; }

    const int m4 = (4*p) % 720;
    float dstep_s, dstep_c; sincosf((float)m4 * TH, &dstep_s, &dstep_c);

    // even residues r=0,2: split cos/sin sums P,S
    #pragma unroll
    for (int ri = 0; ri < 2; ++ri) {
      const int r = ri*2;
      const float tau = (ri==0)? 1.0f : -1.0f;
      const int kst = k0 + ((r - (k0 & 3) + 4) & 3);
      if (kst > k1) continue;
      float P[4]={0,0,0,0}, S[4]={0,0,0,0};
      float sv, cv; sincosf((float)((kst * p) % 720) * TH, &sv, &cv);
      #pragma unroll 2
      for (int k = kst; k <= k1; k += 4) {
        const float4 d01 = *(const float4*)&SD[k - k0][zh*4 + 0][0];
        const float4 d23 = *(const float4*)&SD[k - k0][zh*4 + 2][0];
        P[0]=fmaf(d01.x,cv,P[0]); S[0]=fmaf(d01.y,sv,S[0]);
        P[1]=fmaf(d01.z,cv,P[1]); S[1]=fmaf(d01.w,sv,S[1]);
        P[2]=fmaf(d23.x,cv,P[2]); S[2]=fmaf(d23.y,sv,S[2]);
        P[3]=fmaf(d23.z,cv,P[3]); S[3]=fmaf(d23.w,sv,S[3]);
        float nc = fmaf(cv, dstep_c, -sv*dstep_s);   // forward +4p*theta
        float ns = fmaf(sv, dstep_c,  cv*dstep_s);
        cv = nc; sv = ns;
      }
      #pragma unroll
      for (int j=0;j<4;++j){
        const float hx = P[j] + S[j];
        const float hm = (ri==0) ? (P[j] - S[j]) : (S[j] - P[j]);
        lx0[j]+=hx; lx2[j]+=hx; lx1[j]+=tau*hx; lx3[j]+=tau*hx;
        lm0[j]+=hm; lm2[j]+=hm; lm1[j]+=tau*hm; lm3[j]+=tau*hm;
      }
    }
    // odd residues r=1,3: 4 split sums Cc,Cs,Sc,Ss
    #pragma unroll
    for (int ri = 0; ri < 2; ++ri) {
      const int r = ri*2 + 1;
      const float sig = (ri==0)? 1.0f : -1.0f;
      const int kst = k0 + ((r - (k0 & 3) + 4) & 3);
      if (kst > k1) continue;
      float Cc[4]={0,0,0,0}, Cs[4]={0,0,0,0}, Sc[4]={0,0,0,0}, Ss[4]={0,0,0,0};
      float sv, cv; sincosf((float)((kst * p) % 720) * TH, &sv, &cv);
      #pragma unroll 2
      for (int k = kst; k <= k1; k += 4) {
        const float4 d01 = *(const float4*)&SD[k - k0][zh*4 + 0][0];
        const float4 d23 = *(const float4*)&SD[k - k0][zh*4 + 2][0];
        Cc[0]=fmaf(d01.x,cv,Cc[0]); Cs[0]=fmaf(d01.x,sv,Cs[0]);
        Sc[0]=fmaf(d01.y,cv,Sc[0]); Ss[0]=fmaf(d01.y,sv,Ss[0]);
        Cc[1]=fmaf(d01.z,cv,Cc[1]); Cs[1]=fmaf(d01.z,sv,Cs[1]);
        Sc[1]=fmaf(d01.w,cv,Sc[1]); Ss[1]=fmaf(d01.w,sv,Ss[1]);
        Cc[2]=fmaf(d23.x,cv,Cc[2]); Cs[2]=fmaf(d23.x,sv,Cs[2]);
        Sc[2]=fmaf(d23.y,cv,Sc[2]); Ss[2]=fmaf(d23.y,sv,Ss[2]);
        Cc[3]=fmaf(d23.z,cv,Cc[3]); Cs[3]=fmaf(d23.z,sv,Cs[3]);
        Sc[3]=fmaf(d23.w,cv,Sc[3]); Ss[3]=fmaf(d23.w,sv,Ss[3]);
        float nc = fmaf(cv, dstep_c, -sv*dstep_s);
        float ns = fmaf(sv, dstep_c,  cv*dstep_s);
        cv = nc; sv = ns;
      }
      #pragma unroll
      for (int j=0;j<4;++j){
        const float hrx = Cc[j] + Ss[j];
        const float hix = Sc[j] - Cs[j];
        const float hrm = sig*(Cs[j] + Sc[j]);
        const float him = Ss[j] - Cc[j];      // sig^2 = 1 on l1/l3 combine
        lx0[j]+=hrx; lx2[j]-=hrx; lx1[j]+=sig*hix; lx3[j]-=sig*hix;
        lm0[j]+=hrm; lm2[j]-=hrm; lm1[j]+=him;     lm3[j]-=him;
      }
    }

    const float inv = 1.0f/720.0f;
    // recover original field values (subtract mode) from folded arrays
    float qx[4][4], qm[4][4];
    if (!keep) {
      const int o = p*8 + zh*4;
      #pragma unroll
      for (int j=0;j<4;++j){
        const float s0x = 0.5f*(S0p[o+j] + S0m[o+j]);
        const float s0M = 0.5f*(S0p[o+j] - S0m[o+j]);
        const float s2x = 0.5f*(S2p[o+j] + S2m[o+j]);
        const float s2M = 0.5f*(S2p[o+j] - S2m[o+j]);
        const float Ax  = 0.5f*(Q1a[o+j] + Q4a[o+j]);
        const float AM  = 0.5f*(Q2a[o+j] + Q3a[o+j]);
        const float Bx  = 0.5f*(Q3a[o+j] - Q2a[o+j]);
        const float BM  = 0.5f*(Q4a[o+j] - Q1a[o+j]);
        { const float sp = 0.25f*(s0x + s2x), sm = 0.25f*(s0x - s2x);
          qx[0][j] = sp + 0.5f*Ax; qx[1][j] = sm + 0.5f*Bx;
          qx[2][j] = sp - 0.5f*Ax; qx[3][j] = sm - 0.5f*Bx; }
        { const float sp = 0.25f*(s0M + s2M), sm = 0.25f*(s0M - s2M);
          qm[0][j] = sp + 0.5f*AM; qm[1][j] = sm + 0.5f*BM;
          qm[2][j] = sp - 0.5f*AM; qm[3][j] = sm - 0.5f*BM; }
      }
    }
    // x = p outputs
    {
      float o[4][4];
      #pragma unroll
      for (int j=0;j<4;++j){
        float l0 = lx0[j]*inv, l1 = lx1[j]*inv, l2 = lx2[j]*inv, l3 = lx3[j]*inv;
        if (!keep) { l0 = qx[0][j]-l0; l1 = qx[1][j]-l1; l2 = qx[2][j]-l2; l3 = qx[3][j]-l3; }
        o[0][j] = fminf(fmaxf(l0,-clipv),clipv);
        o[1][j] = fminf(fmaxf(l1,-clipv),clipv);
        o[2][j] = fminf(fmaxf(l2,-clipv),clipv);
        o[3][j] = fminf(fmaxf(l3,-clipv),clipv);
      }
      #pragma unroll
      for (int jj=0;jj<4;++jj)
        *(float4*)(base + (size_t)(p + 180*jj)*NZ + zh*4) =
            make_float4(o[jj][0], o[jj][1], o[jj][2], o[jj][3]);
    }
    // mirror x = 180-p outputs
    if (hasm) {
      const int xm = 180 - p;
      float o[4][4];
      #pragma unroll
      for (int j=0;j<4;++j){
        float l0 = lm0[j]*inv, l1 = lm1[j]*inv, l2 = lm2[j]*inv, l3 = lm3[j]*inv;
        if (!keep) { l0 = qm[0][j]-l0; l1 = qm[1][j]-l1; l2 = qm[2][j]-l2; l3 = qm[3][j]-l3; }
        o[0][j] = fminf(fmaxf(l0,-clipv),clipv);
        o[1][j] = fminf(fmaxf(l1,-clipv),clipv);
        o[2][j] = fminf(fmaxf(l2,-clipv),clipv);
        o[3][j] = fminf(fmaxf(l3,-clipv),clipv);
      }
      #pragma unroll
      for (int jj=0;jj<4;++jj)
        *(float4*)(base + (size_t)(xm + 180*jj)*NZ + zh*4) =
            make_float4(o[jj][0], o[jj][1], o[jj][2], o[jj][3]);
    }
  }
}

// -------------------- host --------------------
extern "C" void kernel_launch(void* const* d_in, const int* in_sizes, int n_in,
                              void* d_out, int out_size, void* d_ws, size_t ws_size,
                              hipStream_t stream) {
  (void)in_sizes; (void)n_in; (void)d_ws; (void)ws_size; (void)out_size;
  const float* u  = (const float*)d_in[0];
  const float* v  = (const float*)d_in[1];
  const float* T  = (const float*)d_in[2];
  const float* ps = (const float*)d_in[4];
  const float* Rp = (const float*)d_in[6];

  float* out = (float*)d_out;
  float* du  = out;
  float* dv  = out + (size_t)NPTS;
  float* dT  = out + (size_t)2*NPTS;
  float* dq  = out + (size_t)3*NPTS;   // staged as div_h scratch; zeroed in filter
  float* dps = out + (size_t)4*NPTS;

  k_divh<<<NPTS/256, 256, 0, stream>>>(u, v, dq);
  k_tend<<<NCOL/8,   256, 0, stream>>>(u, v, T, ps, Rp, dq, du, dv, dT, dps);
  k_filter4b<<<9376, 384, 0, stream>>>(du, dv, dT, dps, dq);
}

// Round 14
// 434.431 us; speedup vs baseline: 1.4813x; 1.0591x over previous
//
#include <hip/hip_runtime.h>
#include <math.h>

#define NB 2
#define NY 360
#define NX 720
#define NZ 32
#define NPTS (NB*NY*NX*NZ)     // 16,588,800
#define NCOL (NB*NY*NX)        // 518,400

__device__ __forceinline__ int i4(int b,int y,int x,int z){ return (((b*NY)+y)*NX+x)*NZ+z; }
__device__ __forceinline__ int i3(int b,int y,int x){ return ((b*NY)+y)*NX+x; }

#define F_RAD   6371000.0f
#define F_OMEGA 7.292e-5f
#define F_CP    1004.0f
#define F_DLAT  ((float)(M_PI/360.0))                 /* == dlon */
#define F_DYR   ((float)(M_PI/360.0*6371000.0))      /* dlat*RAD */
#define F_HPI   ((float)(M_PI/2.0))
#define TH      ((float)(2.0*M_PI/720.0))

// -------------------- kernel 1: div_h = du/dx + dv/dy (float4 over z) -----
// 16200 blocks (8*2025 chunked XCD swizzle); thread = one z-quad.
__global__ __launch_bounds__(256) void k_divh(const float* __restrict__ u,
                                              const float* __restrict__ v,
                                              float* __restrict__ divh) {
  const int bswz = (blockIdx.x & 7) * 2025 + (blockIdx.x >> 3);
  const int idx = bswz*256 + threadIdx.x;          // quad index: NPTS/4 total
  const int zq = idx & 7;
  const int x  = (idx >> 3) % NX;
  const int by = idx / (NX*8);
  const int y  = by % NY;
  const int b  = by / NY;
  const float lat = -F_HPI + (y+0.5f)*F_DLAT;
  const float cl  = cosf(lat);
  const float invdx = 0.5f/(F_DLAT*F_RAD*cl);
  const int xp = (x==NX-1)?0:x+1, xm = (x==0)?NX-1:x-1;
  const float4 uxp = *(const float4*)&u[i4(b,y,xp,zq*4)];
  const float4 uxm = *(const float4*)&u[i4(b,y,xm,zq*4)];
  float4 vyp, vym; float cy;
  if (y == 0)          { vyp = *(const float4*)&v[i4(b,1,x,zq*4)];    vym = *(const float4*)&v[i4(b,0,x,zq*4)];    cy = 1.0f/F_DYR; }
  else if (y == NY-1)  { vyp = *(const float4*)&v[i4(b,NY-1,x,zq*4)]; vym = *(const float4*)&v[i4(b,NY-2,x,zq*4)]; cy = 1.0f/F_DYR; }
  else                 { vyp = *(const float4*)&v[i4(b,y+1,x,zq*4)];  vym = *(const float4*)&v[i4(b,y-1,x,zq*4)];  cy = 0.5f/F_DYR; }
  float4 o;
  o.x = (uxp.x - uxm.x)*invdx + (vyp.x - vym.x)*cy;
  o.y = (uxp.y - uxm.y)*invdx + (vyp.y - vym.y)*cy;
  o.z = (uxp.z - uxm.z)*invdx + (vyp.z - vym.z)*cy;
  o.w = (uxp.w - uxm.w)*invdx + (vyp.w - vym.w)*cy;
  *(float4*)&divh[idx*4] = o;
}

// -------------------- kernel 2: all raw tendencies --------------------
// sufscan linearity: dphidx = sufscan(R*rz*dTdx), dphidy = sufscan(R*rz*dTdy)
// (suffix-scan commutes with the linear stencils) -> 5 scans reduced to 2.
__global__ __launch_bounds__(256) void k_tend(
    const float* __restrict__ u, const float* __restrict__ v,
    const float* __restrict__ T, const float* __restrict__ ps,
    const float* __restrict__ Rp, const float* __restrict__ divh,
    float* __restrict__ du, float* __restrict__ dv,
    float* __restrict__ dT, float* __restrict__ dps) {
  const int tid = threadIdx.x;
  const int z   = tid & 31;
  const int bswz = (blockIdx.x & 7) * 8100 + (blockIdx.x >> 3);
  const int col = bswz*8 + (tid>>5);               // exact: 64800*8 = NCOL
  const int x = col % NX;
  const int y = (col / NX) % NY;
  const int b = col / (NX*NY);
  const float R = Rp[0];

  const int xp = (x==NX-1)?0:x+1, xm = (x==0)?NX-1:x-1;
  const int ycm = (y>0)? y-1 : 0;
  const int ycp = (y<NY-1)? y+1 : NY-1;
  const bool y0 = (y==0), yN = (y==NY-1);

  const float lat  = -F_HPI + (y+0.5f)*F_DLAT;
  const float cl   = cosf(lat);
  const float fcor = 2.0f*F_OMEGA*sinf(lat);
  const float sx     = F_DLAT*F_RAD*cl;
  const float invdx  = 0.5f/sx;
  const float inv2dy = 0.5f/F_DYR;
  const float inv1dy = 1.0f/F_DYR;
  const float invsx2 = 1.0f/(sx*sx);
  const float invsy2 = 1.0f/(F_DYR*F_DYR);
  const float bk  = (z + 0.5f)/32.0f;
  const float dsv = 1.0f/32.0f;

  const int ic  = i4(b,y,x,z),   ixp = i4(b,y,xp,z), ixm = i4(b,y,xm,z);
  const int iyp = i4(b,ycp,x,z), iym = i4(b,ycm,x,z);

  const float uc=u[ic], uxp=u[ixp], uxm=u[ixm], uyp=u[iyp], uym=u[iym];
  const float vc=v[ic], vxp=v[ixp], vxm=v[ixm], vyp=v[iyp], vym=v[iym];
  const float Tc=T[ic], Txp=T[ixp], Txm=T[ixm], Typ=T[iyp], Tym=T[iym];
  const float Dc=divh[ic], Dxp=divh[ixp], Dxm=divh[ixm], Dyp=divh[iyp], Dym=divh[iym];
  const float psc=ps[i3(b,y,x)],   psxp=ps[i3(b,y,xp)], psxm=ps[i3(b,y,xm)];
  const float psyp=ps[i3(b,ycp,x)], psym=ps[i3(b,ycm,x)];

  auto dfy = [&](float fc_, float fyp_, float fym_) -> float {
    if (y0) return (fyp_ - fc_) * inv1dy;
    if (yN) return (fc_ - fym_) * inv1dy;
    return (fyp_ - fym_) * inv2dy;
  };
  auto lap = [&](float fc_, float fxp_, float fxm_, float fyp_, float fym_) -> float {
    float d2x = (fxp_ + fxm_ - 2.0f*fc_) * invsx2;
    float d2y = (y0||yN) ? 0.0f : (fyp_ + fym_ - 2.0f*fc_) * invsy2;
    return d2x + d2y;
  };
  auto sufscan = [&](float vv) -> float {   // vv[z] = sum_{j>=z}
    #pragma unroll
    for (int d=1; d<32; d<<=1) { float t = __shfl_down(vv, d, 32); if (z+d<32) vv += t; }
    return vv;
  };
  auto prescan = [&](float vv) -> float {   // vv[z] = sum_{j<=z}
    #pragma unroll
    for (int d=1; d<32; d<<=1) { float t = __shfl_up(vv, d, 32); if (z>=d) vv += t; }
    return vv;
  };
  auto vg = [&](float fc_) -> float {       // d/dsigma
    float fzp = __shfl_down(fc_,1,32), fzm = __shfl_up(fc_,1,32);
    if (z==0)  return (fzp - fc_) * 32.0f;
    if (z==31) return (fc_ - fzm) * 32.0f;
    return (fzp - fzm) * 16.0f;
  };

  const float dudx = (uxp-uxm)*invdx, dvdx = (vxp-vxm)*invdx, dTdx = (Txp-Txm)*invdx;
  const float dudy = dfy(uc,uyp,uym), dvdy_ = dfy(vc,vyp,vym), dTdy = dfy(Tc,Typ,Tym);
  const float dpsdx = (psxp-psxm)*invdx, dpsdy = dfy(psc,psyp,psym);
  const float gdivx = (Dxp-Dxm)*invdx,  gdivy = dfy(Dc,Dyp,Dym);

  const float rz = dsv / bk;
  const float dphidx = sufscan(R*rz*dTdx);
  const float dphidy = sufscan(R*rz*dTdy);

  const float mass = Dc*psc + uc*dpsdx + vc*dpsdy;
  float Ipre = prescan(mass) * dsv;
  const float Itot = __shfl(Ipre, 31, 32);
  const float sigd = (bk*Itot - Ipre) / (psc + 1e-8f);

  const float vgu = vg(uc), vgv = vg(vc), vgT = vg(Tc);

  const float pfac = R*Tc*bk/(bk*psc + 1e-8f);
  const float pgfu = -dphidx - pfac*dpsdx;
  const float pgfv = -dphidy - pfac*dpsdy;
  const float cf2  = fmaxf(cl*cl, 0.01f);
  const float nudiv = 500000.0f*cf2, nuh = 100000.0f*cf2;
  const float lapu = lap(uc,uxp,uxm,uyp,uym);
  const float lapv = lap(vc,vxp,vxm,vyp,vym);
  const float lapT = lap(Tc,Txp,Txm,Typ,Tym);
  const float adiab = R*Tc/(bk*psc*F_CP + 1e-8f) * (sigd*psc);

  float dut = -(uc*dudx + vc*dudy)  - sigd*vgu + fcor*vc + pgfu + nuh*lapu - 1e-5f*uc + nudiv*gdivx;
  float dvt = -(uc*dvdx + vc*dvdy_) - sigd*vgv - fcor*uc + pgfv + nuh*lapv - 1e-5f*vc + nudiv*gdivy;
  float dTt = -(uc*dTdx + vc*dTdy)  - sigd*vgT + adiab + nuh*lapT;

  du[ic] = dut; dv[ic] = dvt; dT[ic] = dTt;
  if (z == 0) dps[i3(b,y,x)] = -Itot;
}

// -------------------- polar filter helpers --------------------
__device__ __forceinline__ void filter_band(int y, int& k0, int& k1, bool& keepmode) {
  float lat = -F_HPI + (y+0.5f)*F_DLAT;
  float cut = fmaxf(360.0f*cosf(lat), 1.0f);
  int M = (int)floorf(cut);
  keepmode = (M <= 179);
  k0 = keepmode ? 0 : (M+1);
  k1 = keepmode ? M : 360;
}

// -------------------- kernel 3: folded-DFT polar filter (R13, unchanged) --
#define FKMAX 180
__global__ __launch_bounds__(384, 4) void k_filter4b(
    float* __restrict__ du, float* __restrict__ dv, float* __restrict__ dT,
    float* __restrict__ dps, float* __restrict__ dq) {
  __shared__ __align__(16) float smem[8704];   // 34.816 KB

  const int tid = threadIdx.x;
  const int xcd = blockIdx.x & 7;
  const int s   = blockIdx.x >> 3;                 // 0..1171
  const int bid = ((s >> 2) * 8 + xcd) * 4 + (s & 3);
  if (bid >= 9360) return;

  if (bid >= 8640) {
    // ---------------- dpsdt filter path (720 blocks) ----------------
    float*  f  = smem;                          // [720]
    float2* tw = (float2*)(smem + 720);         // [720]
    float*  sc = smem + 720 + 1440;             // [184]
    float*  ss = sc + 184;
    const int row = bid - 8640;                 // 0..719 = b*360+y
    const int y = row % NY;
    float* base = dps + (size_t)row*NX;
    for (int t = tid; t < NX; t += 384) {
      float a = (float)t * TH;
      float sv, cv; sincosf(a, &sv, &cv);
      tw[t] = make_float2(cv, sv);
      f[t] = base[t];
    }
    int k0, k1; bool keepmode;
    filter_band(y, k0, k1, keepmode);
    const int nk = k1 - k0 + 1;
    __syncthreads();
    if (tid < nk) {
      const int k = k0 + tid;
      float ac=0.f, as=0.f; int idx=0;
      for (int xx=0; xx<NX; ++xx) {
        const float fv = f[xx];
        const float2 t2 = tw[idx];
        ac = fmaf(fv, t2.x, ac); as = fmaf(fv, t2.y, as);
        idx += k; if (idx >= NX) idx -= NX;
      }
      sc[tid]=ac; ss[tid]=as;
    }
    __syncthreads();
    if (tid < 360) {
      const int x0 = tid, x1 = tid + 360;
      const int t0 = (x0 * k0) % NX;
      const int t1 = (x1 * k0) % NX;
      float c0 = tw[t0].x, s0 = tw[t0].y;
      float c1 = tw[t1].x, s1 = tw[t1].y;
      const float dc0 = tw[x0].x, dn0 = tw[x0].y;
      const float dc1 = tw[x1].x, dn1 = tw[x1].y;
      float a0 = 0.f, a1 = 0.f;
      for (int kk = 0; kk < nk; ++kk) {
        const int k = k0 + kk;
        const float w = (k==0 || k==360) ? 1.0f : 2.0f;
        a0 = fmaf(sc[kk], w*c0, fmaf(ss[kk], w*s0, a0));
        a1 = fmaf(sc[kk], w*c1, fmaf(ss[kk], w*s1, a1));
        float n0 = c0*dc0 - s0*dn0; s0 = c0*dn0 + s0*dc0; c0 = n0;
        float n1 = c1*dc1 - s1*dn1; s1 = c1*dn1 + s1*dc1; c1 = n1;
      }
      const float inv = 1.0f/720.0f;
      float o0 = keepmode ? a0*inv : f[x0] - a0*inv;
      float o1 = keepmode ? a1*inv : f[x1] - a1*inv;
      o0 = fminf(fmaxf(o0, -0.5f), 0.5f);
      o1 = fminf(fmaxf(o1, -0.5f), 0.5f);
      base[x0] = o0;
      base[x1] = o1;
    }
    return;
  }

  // ---------------- field filter path (8640 blocks) ----------------
  float* S0p = smem + 0;       // [91][8]
  float* S0m = smem + 728;
  float* S2p = smem + 1456;
  float* S2m = smem + 2184;
  float* Q1a = smem + 2912;
  float* Q2a = smem + 3640;
  float* Q3a = smem + 4368;
  float* Q4a = smem + 5096;
  float (*SD)[8][2] = (float(*)[8][2])(smem + 5824);  // [180][8][2]

  // fused k_zero: each field block zeroes its 1920-float dq slice
  {
    float4* dqv = (float4*)dq + (size_t)bid * 480;
    const float4 z4 = make_float4(0.f,0.f,0.f,0.f);
    for (int t = tid; t < 480; t += 384) dqv[t] = z4;
  }

  const int zq   = bid & 3;
  const int rest = bid >> 2;
  const int by   = rest % (NB*NY);
  const int fld  = rest / (NB*NY);
  const int y = by % NY, b = by / NY;
  float* fptr = (fld==0)? du : (fld==1)? dv : dT;
  const float clipv = (fld==2)? 0.01f : 0.02f;
  float* base = fptr + ((size_t)(b*NY+y)*NX)*NZ + zq*8;

  int k0, k1; bool keep;
  filter_band(y, k0, k1, keep);

  // ---- load + fold4 + mirror-fold (tid<182: pair-slot p, z-half zh) ----
  if (tid < 182) {
    const int p  = tid % 91;
    const int zh = tid / 91;
    const bool hasm = (p >= 1 && p <= 89);
    const int xm = 180 - p;
    const float4 q0 = *(const float4*)(base + (size_t)(p      )*NZ + zh*4);
    const float4 q1 = *(const float4*)(base + (size_t)(p + 180)*NZ + zh*4);
    const float4 q2 = *(const float4*)(base + (size_t)(p + 360)*NZ + zh*4);
    const float4 q3 = *(const float4*)(base + (size_t)(p + 540)*NZ + zh*4);
    float4 m0 = make_float4(0,0,0,0), m1 = m0, m2 = m0, m3 = m0;
    if (hasm) {
      m0 = *(const float4*)(base + (size_t)(xm      )*NZ + zh*4);
      m1 = *(const float4*)(base + (size_t)(xm + 180)*NZ + zh*4);
      m2 = *(const float4*)(base + (size_t)(xm + 360)*NZ + zh*4);
      m3 = *(const float4*)(base + (size_t)(xm + 540)*NZ + zh*4);
    }
    const int o = p*8 + zh*4;
    #pragma unroll
    for (int j = 0; j < 4; ++j) {
      const float a0 = (j==0)?q0.x:(j==1)?q0.y:(j==2)?q0.z:q0.w;
      const float a1 = (j==0)?q1.x:(j==1)?q1.y:(j==2)?q1.z:q1.w;
      const float a2 = (j==0)?q2.x:(j==1)?q2.y:(j==2)?q2.z:q2.w;
      const float a3 = (j==0)?q3.x:(j==1)?q3.y:(j==2)?q3.z:q3.w;
      const float b0 = (j==0)?m0.x:(j==1)?m0.y:(j==2)?m0.z:m0.w;
      const float b1 = (j==0)?m1.x:(j==1)?m1.y:(j==2)?m1.z:m1.w;
      const float b2 = (j==0)?m2.x:(j==1)?m2.y:(j==2)?m2.z:m2.w;
      const float b3 = (j==0)?m3.x:(j==1)?m3.y:(j==2)?m3.z:m3.w;
      const float s0  = a0+a1+a2+a3, s2  = a0-a1+a2-a3, A  = a0-a2, B  = a1-a3;
      const float s0M = b0+b1+b2+b3, s2M = b0-b1+b2-b3, AM = b0-b2, BM = b1-b3;
      S0p[o+j] = s0 + s0M;  S0m[o+j] = s0 - s0M;
      S2p[o+j] = s2 + s2M;  S2m[o+j] = s2 - s2M;
      Q1a[o+j] = A - BM;    Q2a[o+j] = AM - B;
      Q3a[o+j] = AM + B;    Q4a[o+j] = A + BM;
    }
  }
  __syncthreads();

  // ---- analysis: thread = (ks 0..95, xq 0..3); one k, 8 z, 91 slots ----
  {
    const int xq = tid & 3;
    const int ks = tid >> 2;            // 0..95; waves 0-2 even-class, 3-5 odd
    const bool isodd = (ks >= 48);
    const int slot = isodd ? ks - 48 : ks;
    const int ke0 = k0 + (k0 & 1);      // first even >= k0
    const int ko0 = k0 | 1;             // first odd  >= k0
    const int kbase = isodd ? ko0 : ke0;
    const int cnt   = (k1 >= kbase) ? (((k1 - kbase) >> 1) + 1) : 0;
    const bool dual = (cnt > 48);
    int k, x0, xe; bool act;
    if (dual) { k = kbase + 2*(slot + 48*(xq>>1)); x0 = (xq&1)?46:0; xe = (xq&1)?91:46; act = (k <= k1); }
    else      { k = kbase + 2*slot; x0 = 23*xq; xe = (xq==3)?91:(x0+23); act = (slot < cnt); }

    float ac[8], as[8];
    #pragma unroll
    for (int j=0;j<8;++j){ ac[j]=0.f; as[j]=0.f; }

    if (act) {
      float dc, ds; sincosf((float)k * TH, &ds, &dc);
      float c, s;   sincosf((float)((k * x0) % 720) * TH, &s, &c);
      const int n = xe - x0;
      if (!isodd) {
        const int r = k & 3;
        const float* Pc = ((r == 0) ? S0p : S2m) + x0*8;
        const float* Ps = ((r == 0) ? S0m : S2p) + x0*8;
        #pragma unroll 4
        for (int i = 0; i < n; ++i) {
          const float4 c0 = *(const float4*)(Pc + i*8);
          const float4 c1 = *(const float4*)(Pc + i*8 + 4);
          const float4 s0v = *(const float4*)(Ps + i*8);
          const float4 s1v = *(const float4*)(Ps + i*8 + 4);
          ac[0]=fmaf(c0.x ,c,ac[0]); as[0]=fmaf(s0v.x,s,as[0]);
          ac[1]=fmaf(c0.y ,c,ac[1]); as[1]=fmaf(s0v.y,s,as[1]);
          ac[2]=fmaf(c0.z ,c,ac[2]); as[2]=fmaf(s0v.z,s,as[2]);
          ac[3]=fmaf(c0.w ,c,ac[3]); as[3]=fmaf(s0v.w,s,as[3]);
          ac[4]=fmaf(c1.x ,c,ac[4]); as[4]=fmaf(s1v.x,s,as[4]);
          ac[5]=fmaf(c1.y ,c,ac[5]); as[5]=fmaf(s1v.y,s,as[5]);
          ac[6]=fmaf(c1.z ,c,ac[6]); as[6]=fmaf(s1v.z,s,as[6]);
          ac[7]=fmaf(c1.w ,c,ac[7]); as[7]=fmaf(s1v.w,s,as[7]);
          const float nc = fmaf(c, dc, -s*ds);
          s = fmaf(s, dc, c*ds); c = nc;
        }
      } else {
        const float sg = ((k & 3) == 1) ? 1.0f : -1.0f;
        const float* p1 = Q1a + x0*8; const float* p2 = Q2a + x0*8;
        const float* p3 = Q3a + x0*8; const float* p4 = Q4a + x0*8;
        #pragma unroll 2
        for (int i = 0; i < n; ++i) {
          const float4 u10 = *(const float4*)(p1 + i*8);
          const float4 u11 = *(const float4*)(p1 + i*8 + 4);
          const float4 u20 = *(const float4*)(p2 + i*8);
          const float4 u21 = *(const float4*)(p2 + i*8 + 4);
          const float4 u30 = *(const float4*)(p3 + i*8);
          const float4 u31 = *(const float4*)(p3 + i*8 + 4);
          const float4 u40 = *(const float4*)(p4 + i*8);
          const float4 u41 = *(const float4*)(p4 + i*8 + 4);
          const float svs = sg*s, cvs = sg*c;
          ac[0]=fmaf(u10.x,c,fmaf(u20.x,svs,ac[0])); as[0]=fmaf(u30.x,cvs,fmaf(u40.x,s,as[0]));
          ac[1]=fmaf(u10.y,c,fmaf(u20.y,svs,ac[1])); as[1]=fmaf(u30.y,cvs,fmaf(u40.y,s,as[1]));
          ac[2]=fmaf(u10.z,c,fmaf(u20.z,svs,ac[2])); as[2]=fmaf(u30.z,cvs,fmaf(u40.z,s,as[2]));
          ac[3]=fmaf(u10.w,c,fmaf(u20.w,svs,ac[3])); as[3]=fmaf(u30.w,cvs,fmaf(u40.w,s,as[3]));
          ac[4]=fmaf(u11.x,c,fmaf(u21.x,svs,ac[4])); as[4]=fmaf(u31.x,cvs,fmaf(u41.x,s,as[4]));
          ac[5]=fmaf(u11.y,c,fmaf(u21.y,svs,ac[5])); as[5]=fmaf(u31.y,cvs,fmaf(u41.y,s,as[5]));
          ac[6]=fmaf(u11.z,c,fmaf(u21.z,svs,ac[6])); as[6]=fmaf(u31.z,cvs,fmaf(u41.z,s,as[6]));
          ac[7]=fmaf(u11.w,c,fmaf(u21.w,svs,ac[7])); as[7]=fmaf(u31.w,cvs,fmaf(u41.w,s,as[7]));
          const float nc = fmaf(c, dc, -s*ds);
          s = fmaf(s, dc, c*ds); c = nc;
        }
      }
    }
    // combine partial sums over the 4-lane xq group
    #pragma unroll
    for (int j=0;j<8;++j){
      ac[j] += __shfl_xor(ac[j], 1);
      as[j] += __shfl_xor(as[j], 1);
    }
    if (!dual) {
      #pragma unroll
      for (int j=0;j<8;++j){
        ac[j] += __shfl_xor(ac[j], 2);
        as[j] += __shfl_xor(as[j], 2);
      }
    }
    if (act && ((xq & (dual ? 1 : 3)) == 0)) {
      const float w = (k==0 || k==360) ? 1.0f : 2.0f;
      const int r = k - k0;
      *(float4*)&SD[r][0][0] = make_float4(w*ac[0], w*as[0], w*ac[1], w*as[1]);
      *(float4*)&SD[r][2][0] = make_float4(w*ac[2], w*as[2], w*ac[3], w*as[3]);
      *(float4*)&SD[r][4][0] = make_float4(w*ac[4], w*as[4], w*ac[5], w*as[5]);
      *(float4*)&SD[r][6][0] = make_float4(w*ac[6], w*as[6], w*ac[7], w*as[7]);
    }
  }
  __syncthreads();

  // ---- synthesis: thread = (pair p 0..90, zh 0..1) serves x=p and 180-p ----
  if (tid < 182) {
    const int p  = tid % 91;
    const int zh = tid / 91;
    const bool hasm = (p >= 1 && p <= 89);
    float lx0[4],lx1[4],lx2[4],lx3[4], lm0[4],lm1[4],lm2[4],lm3[4];
    #pragma unroll
    for (int j=0;j<4;++j){ lx0[j]=lx1[j]=lx2[j]=lx3[j]=0.f; lm0[j]=lm1[j]=lm2[j]=lm3[j]=0.f; }

    const int m4 = (4*p) % 720;
    float dstep_s, dstep_c; sincosf((float)m4 * TH, &dstep_s, &dstep_c);

    // even residues r=0,2: split cos/sin sums P,S
    #pragma unroll
    for (int ri = 0; ri < 2; ++ri) {
      const int r = ri*2;
      const float tau = (ri==0)? 1.0f : -1.0f;
      const int kst = k0 + ((r - (k0 & 3) + 4) & 3);
      if (kst > k1) continue;
      float P[4]={0,0,0,0}, S[4]={0,0,0,0};
      float sv, cv; sincosf((float)((kst * p) % 720) * TH, &sv, &cv);
      #pragma unroll 2
      for (int k = kst; k <= k1; k += 4) {
        const float4 d01 = *(const float4*)&SD[k - k0][zh*4 + 0][0];
        const float4 d23 = *(const float4*)&SD[k - k0][zh*4 + 2][0];
        P[0]=fmaf(d01.x,cv,P[0]); S[0]=fmaf(d01.y,sv,S[0]);
        P[1]=fmaf(d01.z,cv,P[1]); S[1]=fmaf(d01.w,sv,S[1]);
        P[2]=fmaf(d23.x,cv,P[2]); S[2]=fmaf(d23.y,sv,S[2]);
        P[3]=fmaf(d23.z,cv,P[3]); S[3]=fmaf(d23.w,sv,S[3]);
        float nc = fmaf(cv, dstep_c, -sv*dstep_s);   // forward +4p*theta
        float ns = fmaf(sv, dstep_c,  cv*dstep_s);
        cv = nc; sv = ns;
      }
      #pragma unroll
      for (int j=0;j<4;++j){
        const float hx = P[j] + S[j];
        const float hm = (ri==0) ? (P[j] - S[j]) : (S[j] - P[j]);
        lx0[j]+=hx; lx2[j]+=hx; lx1[j]+=tau*hx; lx3[j]+=tau*hx;
        lm0[j]+=hm; lm2[j]+=hm; lm1[j]+=tau*hm; lm3[j]+=tau*hm;
      }
    }
    // odd residues r=1,3: 4 split sums Cc,Cs,Sc,Ss
    #pragma unroll
    for (int ri = 0; ri < 2; ++ri) {
      const int r = ri*2 + 1;
      const float sig = (ri==0)? 1.0f : -1.0f;
      const int kst = k0 + ((r - (k0 & 3) + 4) & 3);
      if (kst > k1) continue;
      float Cc[4]={0,0,0,0}, Cs[4]={0,0,0,0}, Sc[4]={0,0,0,0}, Ss[4]={0,0,0,0};
      float sv, cv; sincosf((float)((kst * p) % 720) * TH, &sv, &cv);
      #pragma unroll 2
      for (int k = kst; k <= k1; k += 4) {
        const float4 d01 = *(const float4*)&SD[k - k0][zh*4 + 0][0];
        const float4 d23 = *(const float4*)&SD[k - k0][zh*4 + 2][0];
        Cc[0]=fmaf(d01.x,cv,Cc[0]); Cs[0]=fmaf(d01.x,sv,Cs[0]);
        Sc[0]=fmaf(d01.y,cv,Sc[0]); Ss[0]=fmaf(d01.y,sv,Ss[0]);
        Cc[1]=fmaf(d01.z,cv,Cc[1]); Cs[1]=fmaf(d01.z,sv,Cs[1]);
        Sc[1]=fmaf(d01.w,cv,Sc[1]); Ss[1]=fmaf(d01.w,sv,Ss[1]);
        Cc[2]=fmaf(d23.x,cv,Cc[2]); Cs[2]=fmaf(d23.x,sv,Cs[2]);
        Sc[2]=fmaf(d23.y,cv,Sc[2]); Ss[2]=fmaf(d23.y,sv,Ss[2]);
        Cc[3]=fmaf(d23.z,cv,Cc[3]); Cs[3]=fmaf(d23.z,sv,Cs[3]);
        Sc[3]=fmaf(d23.w,cv,Sc[3]); Ss[3]=fmaf(d23.w,sv,Ss[3]);
        float nc = fmaf(cv, dstep_c, -sv*dstep_s);
        float ns = fmaf(sv, dstep_c,  cv*dstep_s);
        cv = nc; sv = ns;
      }
      #pragma unroll
      for (int j=0;j<4;++j){
        const float hrx = Cc[j] + Ss[j];
        const float hix = Sc[j] - Cs[j];
        const float hrm = sig*(Cs[j] + Sc[j]);
        const float him = Ss[j] - Cc[j];
        lx0[j]+=hrx; lx2[j]-=hrx; lx1[j]+=sig*hix; lx3[j]-=sig*hix;
        lm0[j]+=hrm; lm2[j]-=hrm; lm1[j]+=him;     lm3[j]-=him;
      }
    }

    const float inv = 1.0f/720.0f;
    // recover original field values (subtract mode) from folded arrays
    float qx[4][4], qm[4][4];
    if (!keep) {
      const int o = p*8 + zh*4;
      #pragma unroll
      for (int j=0;j<4;++j){
        const float s0x = 0.5f*(S0p[o+j] + S0m[o+j]);
        const float s0M = 0.5f*(S0p[o+j] - S0m[o+j]);
        const float s2x = 0.5f*(S2p[o+j] + S2m[o+j]);
        const float s2M = 0.5f*(S2p[o+j] - S2m[o+j]);
        const float Ax  = 0.5f*(Q1a[o+j] + Q4a[o+j]);
        const float AM  = 0.5f*(Q2a[o+j] + Q3a[o+j]);
        const float Bx  = 0.5f*(Q3a[o+j] - Q2a[o+j]);
        const float BM  = 0.5f*(Q4a[o+j] - Q1a[o+j]);
        { const float sp = 0.25f*(s0x + s2x), sm = 0.25f*(s0x - s2x);
          qx[0][j] = sp + 0.5f*Ax; qx[1][j] = sm + 0.5f*Bx;
          qx[2][j] = sp - 0.5f*Ax; qx[3][j] = sm - 0.5f*Bx; }
        { const float sp = 0.25f*(s0M + s2M), sm = 0.25f*(s0M - s2M);
          qm[0][j] = sp + 0.5f*AM; qm[1][j] = sm + 0.5f*BM;
          qm[2][j] = sp - 0.5f*AM; qm[3][j] = sm - 0.5f*BM; }
      }
    }
    // x = p outputs
    {
      float o[4][4];
      #pragma unroll
      for (int j=0;j<4;++j){
        float l0 = lx0[j]*inv, l1 = lx1[j]*inv, l2 = lx2[j]*inv, l3 = lx3[j]*inv;
        if (!keep) { l0 = qx[0][j]-l0; l1 = qx[1][j]-l1; l2 = qx[2][j]-l2; l3 = qx[3][j]-l3; }
        o[0][j] = fminf(fmaxf(l0,-clipv),clipv);
        o[1][j] = fminf(fmaxf(l1,-clipv),clipv);
        o[2][j] = fminf(fmaxf(l2,-clipv),clipv);
        o[3][j] = fminf(fmaxf(l3,-clipv),clipv);
      }
      #pragma unroll
      for (int jj=0;jj<4;++jj)
        *(float4*)(base + (size_t)(p + 180*jj)*NZ + zh*4) =
            make_float4(o[jj][0], o[jj][1], o[jj][2], o[jj][3]);
    }
    // mirror x = 180-p outputs
    if (hasm) {
      const int xm = 180 - p;
      float o[4][4];
      #pragma unroll
      for (int j=0;j<4;++j){
        float l0 = lm0[j]*inv, l1 = lm1[j]*inv, l2 = lm2[j]*inv, l3 = lm3[j]*inv;
        if (!keep) { l0 = qm[0][j]-l0; l1 = qm[1][j]-l1; l2 = qm[2][j]-l2; l3 = qm[3][j]-l3; }
        o[0][j] = fminf(fmaxf(l0,-clipv),clipv);
        o[1][j] = fminf(fmaxf(l1,-clipv),clipv);
        o[2][j] = fminf(fmaxf(l2,-clipv),clipv);
        o[3][j] = fminf(fmaxf(l3,-clipv),clipv);
      }
      #pragma unroll
      for (int jj=0;jj<4;++jj)
        *(float4*)(base + (size_t)(xm + 180*jj)*NZ + zh*4) =
            make_float4(o[jj][0], o[jj][1], o[jj][2], o[jj][3]);
    }
  }
}

// -------------------- host --------------------
extern "C" void kernel_launch(void* const* d_in, const int* in_sizes, int n_in,
                              void* d_out, int out_size, void* d_ws, size_t ws_size,
                              hipStream_t stream) {
  (void)in_sizes; (void)n_in; (void)d_ws; (void)ws_size; (void)out_size;
  const float* u  = (const float*)d_in[0];
  const float* v  = (const float*)d_in[1];
  const float* T  = (const float*)d_in[2];
  const float* ps = (const float*)d_in[4];
  const float* Rp = (const float*)d_in[6];

  float* out = (float*)d_out;
  float* du  = out;
  float* dv  = out + (size_t)NPTS;
  float* dT  = out + (size_t)2*NPTS;
  float* dq  = out + (size_t)3*NPTS;   // staged as div_h scratch; zeroed in filter
  float* dps = out + (size_t)4*NPTS;

  k_divh<<<NPTS/(256*4), 256, 0, stream>>>(u, v, dq);
  k_tend<<<NCOL/8,       256, 0, stream>>>(u, v, T, ps, Rp, dq, du, dv, dT, dps);
  k_filter4b<<<9376, 384, 0, stream>>>(du, dv, dT, dps, dq);
}